// Round 1
// baseline (1106.184 us; speedup 1.0000x reference)
//
#include <hip/hip_runtime.h>
#include <hip/hip_bf16.h>

#define B_  2
#define L_  2048
#define D_  1024
#define H_  16
#define DH_ 64
#define M_  (B_*L_)     // 4096
#define N1_ (3*D_)      // 3072

__device__ __forceinline__ float4 ld4(const float* p) { return *(const float4*)p; }

// ---------------------------------------------------------------------------
// 128x128x16 fp32 SGEMM, 256 threads, 8x8 per thread.
// EPI==0: plain row-major C [M][NDIM].  EPI==1: QKV scatter to [B][H][L][DH].
// ---------------------------------------------------------------------------
template<int NDIM, int EPI>
__global__ __launch_bounds__(256)
void sgemm128(const float* __restrict__ A, const float* __restrict__ Bw,
              float* __restrict__ C0, float* __restrict__ C1, float* __restrict__ C2)
{
    constexpr int K = 1024;
    __shared__ float As[16][132];   // [k][m], padded: store 2-way, read conflict-free
    __shared__ float Bs[16][132];   // [k][n]
    const int t  = threadIdx.x;
    const int tx = t & 15, ty = t >> 4;
    const int m0 = blockIdx.y * 128, n0 = blockIdx.x * 128;

    float acc[8][8];
    #pragma unroll
    for (int i = 0; i < 8; ++i)
        #pragma unroll
        for (int j = 0; j < 8; ++j) acc[i][j] = 0.f;

    for (int kt = 0; kt < K / 16; ++kt) {
        const int k0 = kt * 16;
        // stage A tile (128 rows x 16 k), transposed into As[k][m]
        #pragma unroll
        for (int it = 0; it < 2; ++it) {
            int i   = t + it * 256;          // 0..511
            int row = i >> 2, kq = (i & 3) * 4;
            float4 a4 = ld4(A + (size_t)(m0 + row) * K + k0 + kq);
            As[kq + 0][row] = a4.x; As[kq + 1][row] = a4.y;
            As[kq + 2][row] = a4.z; As[kq + 3][row] = a4.w;
        }
        // stage B tile (16 k x 128 n), natural layout
        #pragma unroll
        for (int it = 0; it < 2; ++it) {
            int i   = t + it * 256;
            int row = i >> 5, nq = (i & 31) * 4;
            float4 b4 = ld4(Bw + (size_t)(k0 + row) * NDIM + n0 + nq);
            *(float4*)&Bs[row][nq] = b4;
        }
        __syncthreads();
        #pragma unroll
        for (int k = 0; k < 16; ++k) {
            float a[8], b[8];
            *(float4*)&a[0] = ld4(&As[k][ty * 8]);
            *(float4*)&a[4] = ld4(&As[k][ty * 8 + 4]);
            *(float4*)&b[0] = ld4(&Bs[k][tx * 8]);
            *(float4*)&b[4] = ld4(&Bs[k][tx * 8 + 4]);
            #pragma unroll
            for (int i = 0; i < 8; ++i)
                #pragma unroll
                for (int j = 0; j < 8; ++j) acc[i][j] += a[i] * b[j];
        }
        __syncthreads();
    }

    if (EPI == 0) {
        #pragma unroll
        for (int i = 0; i < 8; ++i) {
            int m = m0 + ty * 8 + i;
            float* dst = C0 + (size_t)m * NDIM + n0 + tx * 8;
            *(float4*)dst       = make_float4(acc[i][0], acc[i][1], acc[i][2], acc[i][3]);
            *(float4*)(dst + 4) = make_float4(acc[i][4], acc[i][5], acc[i][6], acc[i][7]);
        }
    } else {
        #pragma unroll
        for (int i = 0; i < 8; ++i) {
            int m = m0 + ty * 8 + i;
            int b = m >> 11, l = m & (L_ - 1);
            #pragma unroll
            for (int jq = 0; jq < 2; ++jq) {
                int n     = n0 + tx * 8 + jq * 4;
                int which = n >> 10;
                int hh    = (n >> 6) & (H_ - 1);
                int dh    = n & (DH_ - 1);
                float* base = (which == 0) ? C0 : ((which == 1) ? C1 : C2);
                float* dst  = base + (((size_t)(b * H_ + hh) * L_ + l) * DH_ + dh);
                *(float4*)dst = make_float4(acc[i][jq*4+0], acc[i][jq*4+1],
                                            acc[i][jq*4+2], acc[i][jq*4+3]);
            }
        }
    }
}

// ---------------------------------------------------------------------------
// RoPE in-place on Q and K, layout [B*H][L][64]; half = 32.
// ---------------------------------------------------------------------------
__global__ __launch_bounds__(256)
void rope_kernel(float* __restrict__ q, float* __restrict__ k)
{
    int gid = blockIdx.x * 256 + threadIdx.x;   // B_*H_*L_*32 total
    int j   = gid & 31;
    int l   = (gid >> 5) & (L_ - 1);
    int bh  = gid >> 16;
    size_t base = ((size_t)bh * L_ + l) * DH_;

    float inv = powf(10000.0f, -(float)j * (1.0f / 32.0f));
    float ang = (float)l * inv;
    float s, c;
    sincosf(ang, &s, &c);

    float q1 = q[base + j], q2 = q[base + j + 32];
    q[base + j]      = q1 * c - q2 * s;
    q[base + j + 32] = q2 * c + q1 * s;
    float k1 = k[base + j], k2 = k[base + j + 32];
    k[base + j]      = k1 * c - k2 * s;
    k[base + j + 32] = k2 * c + k1 * s;
}

// ---------------------------------------------------------------------------
// Flash attention fp32. Block = (bh, 32 q-rows), 256 threads.
// thread (r = t>>3, c = t&7): owns q-row r, keys j = c+8*jj, out cols c*8..c*8+7
// ---------------------------------------------------------------------------
__global__ __launch_bounds__(256)
void attn_kernel(const float* __restrict__ q, const float* __restrict__ k,
                 const float* __restrict__ v, float* __restrict__ ao)
{
    __shared__ float Qs[32][68];
    __shared__ float Ks[64][68];
    __shared__ float Vs[64][68];
    __shared__ float Ps[32][68];
    const int t  = threadIdx.x;
    const int r  = t >> 3, c = t & 7;
    const int bh = blockIdx.x;       // b*H + h
    const int qb = blockIdx.y;       // 0..63

    const float* qp = q + ((size_t)bh * L_ + qb * 32) * DH_;
    const float* kp = k + (size_t)bh * L_ * DH_;
    const float* vp = v + (size_t)bh * L_ * DH_;

    for (int i = t; i < 32 * 16; i += 256) {
        int row = i >> 4, dq = (i & 15) * 4;
        *(float4*)&Qs[row][dq] = ld4(qp + row * DH_ + dq);
    }

    float m_r = -INFINITY, l_r = 0.f, O[8];
    #pragma unroll
    for (int i = 0; i < 8; ++i) O[i] = 0.f;

    for (int kb = 0; kb < L_ / 64; ++kb) {
        __syncthreads();   // previous PV reads done before restaging
        for (int i = t; i < 64 * 16; i += 256) {
            int row = i >> 4, dq = (i & 15) * 4;
            *(float4*)&Ks[row][dq] = ld4(kp + (size_t)(kb * 64 + row) * DH_ + dq);
            *(float4*)&Vs[row][dq] = ld4(vp + (size_t)(kb * 64 + row) * DH_ + dq);
        }
        __syncthreads();

        float s[8];
        #pragma unroll
        for (int jj = 0; jj < 8; ++jj) s[jj] = 0.f;
        #pragma unroll
        for (int d4 = 0; d4 < 16; ++d4) {
            float4 q4 = ld4(&Qs[r][d4 * 4]);
            #pragma unroll
            for (int jj = 0; jj < 8; ++jj) {
                float4 k4 = ld4(&Ks[c + 8 * jj][d4 * 4]);
                s[jj] += q4.x * k4.x + q4.y * k4.y + q4.z * k4.z + q4.w * k4.w;
            }
        }
        float pmax = -INFINITY;
        #pragma unroll
        for (int jj = 0; jj < 8; ++jj) { s[jj] *= 0.125f; pmax = fmaxf(pmax, s[jj]); }
        #pragma unroll
        for (int off = 1; off < 8; off <<= 1) pmax = fmaxf(pmax, __shfl_xor(pmax, off, 8));
        float newm  = fmaxf(m_r, pmax);
        float alpha = __expf(m_r - newm);
        float psum  = 0.f;
        #pragma unroll
        for (int jj = 0; jj < 8; ++jj) {
            float p = __expf(s[jj] - newm);
            Ps[r][c + 8 * jj] = p;
            psum += p;
        }
        #pragma unroll
        for (int off = 1; off < 8; off <<= 1) psum += __shfl_xor(psum, off, 8);
        m_r = newm;
        l_r = l_r * alpha + psum;
        #pragma unroll
        for (int i = 0; i < 8; ++i) O[i] *= alpha;
        __syncthreads();   // Ps visible to the whole block before PV

        #pragma unroll 4
        for (int j = 0; j < 64; ++j) {
            float p  = Ps[r][j];
            float4 v0 = ld4(&Vs[j][c * 8]);
            float4 v1 = ld4(&Vs[j][c * 8 + 4]);
            O[0] += p * v0.x; O[1] += p * v0.y; O[2] += p * v0.z; O[3] += p * v0.w;
            O[4] += p * v1.x; O[5] += p * v1.y; O[6] += p * v1.z; O[7] += p * v1.w;
        }
    }

    float inv = 1.0f / l_r;
    int b  = bh >> 4, h = bh & 15;
    int lq = qb * 32 + r;
    float* dst = ao + ((size_t)(b * L_ + lq)) * D_ + h * DH_ + c * 8;
    *(float4*)dst       = make_float4(O[0]*inv, O[1]*inv, O[2]*inv, O[3]*inv);
    *(float4*)(dst + 4) = make_float4(O[4]*inv, O[5]*inv, O[6]*inv, O[7]*inv);
}

// ---------------------------------------------------------------------------
extern "C" void kernel_launch(void* const* d_in, const int* in_sizes, int n_in,
                              void* d_out, int out_size, void* d_ws, size_t ws_size,
                              hipStream_t stream)
{
    const float* x    = (const float*)d_in[0];   // [B][L][D]
    const float* Wqkv = (const float*)d_in[1];   // [D][3D]
    const float* Wo   = (const float*)d_in[2];   // [D][D]
    float* out = (float*)d_out;                  // [B][L][D]

    const size_t NQ = (size_t)B_ * H_ * L_ * DH_;   // 4M floats per tensor
    float* q  = (float*)d_ws;
    float* k  = q + NQ;
    float* v  = k + NQ;
    float* ao = v + NQ;                             // [B][L][D]

    // 1) QKV projection with scatter
    sgemm128<N1_, 1><<<dim3(N1_ / 128, M_ / 128), 256, 0, stream>>>(x, Wqkv, q, k, v);
    // 2) RoPE on Q, K
    rope_kernel<<<(B_ * H_ * L_ * 32) / 256, 256, 0, stream>>>(q, k);
    // 3) flash attention
    attn_kernel<<<dim3(B_ * H_, L_ / 32), 256, 0, stream>>>(q, k, v, ao);
    // 4) output projection
    sgemm128<D_, 0><<<dim3(D_ / 128, M_ / 128), 256, 0, stream>>>(ao, Wo, out, nullptr, nullptr);
}

// Round 2
// 548.231 us; speedup vs baseline: 2.0177x; 2.0177x over previous
//
#include <hip/hip_runtime.h>
#include <hip/hip_bf16.h>

#define B_  2
#define L_  2048
#define D_  1024
#define H_  16
#define DH_ 64
#define M_  (B_*L_)     // 4096
#define N1_ (3*D_)      // 3072

typedef __bf16 bf16x8 __attribute__((ext_vector_type(8)));
typedef float  f32x4  __attribute__((ext_vector_type(4)));
typedef unsigned short ushort_t;

#define MFMA16(a,b,c) __builtin_amdgcn_mfma_f32_16x16x32_bf16((a),(b),(c),0,0,0)

__device__ __forceinline__ float4 ld4(const float* p) { return *(const float4*)p; }

// round-to-nearest-even float -> bf16 bits (no API dependence)
__device__ __forceinline__ ushort_t f2bf(float f) {
    union { float f; unsigned int u; } v; v.f = f;
    unsigned int r = (v.u + 0x7FFFu + ((v.u >> 16) & 1u)) >> 16;
    return (ushort_t)r;
}

// ---------------------------------------------------------------------------
// 128x128x16 fp32 SGEMM (unchanged, known-correct).
// EPI==0: plain row-major C [M][NDIM].  EPI==1: QKV scatter to [B][H][L][DH].
// ---------------------------------------------------------------------------
template<int NDIM, int EPI>
__global__ __launch_bounds__(256)
void sgemm128(const float* __restrict__ A, const float* __restrict__ Bw,
              float* __restrict__ C0, float* __restrict__ C1, float* __restrict__ C2)
{
    constexpr int K = 1024;
    __shared__ float As[16][132];
    __shared__ float Bs[16][132];
    const int t  = threadIdx.x;
    const int tx = t & 15, ty = t >> 4;
    const int m0 = blockIdx.y * 128, n0 = blockIdx.x * 128;

    float acc[8][8];
    #pragma unroll
    for (int i = 0; i < 8; ++i)
        #pragma unroll
        for (int j = 0; j < 8; ++j) acc[i][j] = 0.f;

    for (int kt = 0; kt < K / 16; ++kt) {
        const int k0 = kt * 16;
        #pragma unroll
        for (int it = 0; it < 2; ++it) {
            int i   = t + it * 256;
            int row = i >> 2, kq = (i & 3) * 4;
            float4 a4 = ld4(A + (size_t)(m0 + row) * K + k0 + kq);
            As[kq + 0][row] = a4.x; As[kq + 1][row] = a4.y;
            As[kq + 2][row] = a4.z; As[kq + 3][row] = a4.w;
        }
        #pragma unroll
        for (int it = 0; it < 2; ++it) {
            int i   = t + it * 256;
            int row = i >> 5, nq = (i & 31) * 4;
            float4 b4 = ld4(Bw + (size_t)(k0 + row) * NDIM + n0 + nq);
            *(float4*)&Bs[row][nq] = b4;
        }
        __syncthreads();
        #pragma unroll
        for (int k = 0; k < 16; ++k) {
            float a[8], b[8];
            *(float4*)&a[0] = ld4(&As[k][ty * 8]);
            *(float4*)&a[4] = ld4(&As[k][ty * 8 + 4]);
            *(float4*)&b[0] = ld4(&Bs[k][tx * 8]);
            *(float4*)&b[4] = ld4(&Bs[k][tx * 8 + 4]);
            #pragma unroll
            for (int i = 0; i < 8; ++i)
                #pragma unroll
                for (int j = 0; j < 8; ++j) acc[i][j] += a[i] * b[j];
        }
        __syncthreads();
    }

    if (EPI == 0) {
        #pragma unroll
        for (int i = 0; i < 8; ++i) {
            int m = m0 + ty * 8 + i;
            float* dst = C0 + (size_t)m * NDIM + n0 + tx * 8;
            *(float4*)dst       = make_float4(acc[i][0], acc[i][1], acc[i][2], acc[i][3]);
            *(float4*)(dst + 4) = make_float4(acc[i][4], acc[i][5], acc[i][6], acc[i][7]);
        }
    } else {
        #pragma unroll
        for (int i = 0; i < 8; ++i) {
            int m = m0 + ty * 8 + i;
            int b = m >> 11, l = m & (L_ - 1);
            #pragma unroll
            for (int jq = 0; jq < 2; ++jq) {
                int n     = n0 + tx * 8 + jq * 4;
                int which = n >> 10;
                int hh    = (n >> 6) & (H_ - 1);
                int dh    = n & (DH_ - 1);
                float* base = (which == 0) ? C0 : ((which == 1) ? C1 : C2);
                float* dst  = base + (((size_t)(b * H_ + hh) * L_ + l) * DH_ + dh);
                *(float4*)dst = make_float4(acc[i][jq*4+0], acc[i][jq*4+1],
                                            acc[i][jq*4+2], acc[i][jq*4+3]);
            }
        }
    }
}

// ---------------------------------------------------------------------------
// RoPE: read fp32 q,k -> write bf16 qb (pre-scaled by 1/8), kb. [B*H][L][64]
// ---------------------------------------------------------------------------
__global__ __launch_bounds__(256)
void rope_bf16(const float* __restrict__ q, const float* __restrict__ k,
               ushort_t* __restrict__ qb, ushort_t* __restrict__ kb)
{
    int gid = blockIdx.x * 256 + threadIdx.x;   // B*H*L*32 pairs
    int j   = gid & 31;
    int l   = (gid >> 5) & (L_ - 1);
    int bh  = gid >> 16;
    size_t base = ((size_t)bh * L_ + l) * DH_;

    float inv = powf(10000.0f, -(float)j * (1.0f / 32.0f));
    float ang = (float)l * inv;
    float s, c;
    sincosf(ang, &s, &c);

    float q1 = q[base + j], q2 = q[base + j + 32];
    qb[base + j]      = f2bf((q1 * c - q2 * s) * 0.125f);
    qb[base + j + 32] = f2bf((q2 * c + q1 * s) * 0.125f);
    float k1 = k[base + j], k2 = k[base + j + 32];
    kb[base + j]      = f2bf(k1 * c - k2 * s);
    kb[base + j + 32] = f2bf(k2 * c + k1 * s);
}

// ---------------------------------------------------------------------------
// Transpose V: fp32 [bh][L][64] -> bf16 vt [bh][64][L], 64x64 tiles via LDS.
// ---------------------------------------------------------------------------
__global__ __launch_bounds__(256)
void transpose_v(const float* __restrict__ v, ushort_t* __restrict__ vt)
{
    __shared__ float vs[64][65];
    const int bh = blockIdx.x, lt = blockIdx.y, t = threadIdx.x;
    #pragma unroll
    for (int i = 0; i < 4; ++i) {
        int idx = t + 256 * i;              // 1024 float4
        int row = idx >> 4, c4 = idx & 15;
        float4 x = ld4(v + ((size_t)(bh * L_ + lt * 64 + row) * 64 + c4 * 4));
        vs[row][c4 * 4 + 0] = x.x; vs[row][c4 * 4 + 1] = x.y;
        vs[row][c4 * 4 + 2] = x.z; vs[row][c4 * 4 + 3] = x.w;
    }
    __syncthreads();
    #pragma unroll
    for (int i = 0; i < 16; ++i) {
        int idx = t + 256 * i;              // 4096 elements
        int d = idx >> 6, lc = idx & 63;
        vt[((size_t)(bh * 64 + d)) * L_ + lt * 64 + lc] = f2bf(vs[lc][d]);
    }
}

// ---------------------------------------------------------------------------
// Flash attention, bf16 MFMA 16x16x32. 4 waves/block, 64 q-rows/block,
// KB=64 key tiles. K and V^T tiles in XOR-swizzled LDS; P via per-wave
// swizzled LDS round-trip. Q frags direct from global (A-layout contiguous).
// Layouts (verified m89/m91):
//   A: lane l holds A[l&15][8*(l>>4)+j]   B: lane l holds B[8*(l>>4)+j][l&15]
//   D: lane l reg r -> D[4*(l>>4)+r][l&15]
// ---------------------------------------------------------------------------
__global__ __launch_bounds__(256)
void attn_mfma(const ushort_t* __restrict__ qb, const ushort_t* __restrict__ kb,
               const ushort_t* __restrict__ vt, float* __restrict__ ao)
{
    __shared__ ushort_t Ks[64 * 64];        // [key][d], swizzled
    __shared__ ushort_t Vs[64 * 64];        // [d][key], swizzled
    __shared__ ushort_t Ps[4 * 16 * 64];    // per-wave [16 q][64 key], swizzled

    const int t    = threadIdx.x;
    const int lane = t & 63, wv = t >> 6;
    const int g    = lane >> 4, ln = lane & 15;
    const int bh   = blockIdx.x;
    const int q0   = blockIdx.y * 64 + wv * 16;

    // Q fragments: lane holds Q[q0+ln][32*kk + 8g .. +8)
    const ushort_t* qp = qb + ((size_t)bh * L_ + q0 + ln) * DH_;
    bf16x8 qf0 = *(const bf16x8*)(qp + 8 * g);
    bf16x8 qf1 = *(const bf16x8*)(qp + 32 + 8 * g);

    const ushort_t* kp = kb + (size_t)bh * L_ * DH_;
    const ushort_t* vp = vt + (size_t)bh * DH_ * L_;

    f32x4 O[4];
    #pragma unroll
    for (int n = 0; n < 4; ++n) O[n] = f32x4{0.f, 0.f, 0.f, 0.f};
    float mr[4], lr[4];
    #pragma unroll
    for (int r = 0; r < 4; ++r) { mr[r] = -INFINITY; lr[r] = 0.f; }

    for (int kt = 0; kt < L_ / 64; ++kt) {
        __syncthreads();   // prior PV reads of Ks/Vs complete
        #pragma unroll
        for (int it = 0; it < 2; ++it) {
            int idx = t + it * 256;
            int row = idx >> 3, ch = idx & 7;
            int dst = row * 64 + ((((ch * 16) ^ ((row & 7) << 4))) >> 1);
            *(bf16x8*)&Ks[dst] = *(const bf16x8*)(kp + (size_t)(kt * 64 + row) * 64 + ch * 8);
            *(bf16x8*)&Vs[dst] = *(const bf16x8*)(vp + (size_t)row * L_ + kt * 64 + ch * 8);
        }
        __syncthreads();

        // S = Q K^T : D rows 4g+r (q within wave tile), cols 16n+ln (key)
        f32x4 S[4];
        #pragma unroll
        for (int n = 0; n < 4; ++n) S[n] = f32x4{0.f, 0.f, 0.f, 0.f};
        #pragma unroll
        for (int kk = 0; kk < 2; ++kk) {
            bf16x8 a = kk ? qf1 : qf0;
            #pragma unroll
            for (int n = 0; n < 4; ++n) {
                int row = 16 * n + ln;
                int off = row * 64 + (((64 * kk + 16 * g) ^ ((row & 7) << 4)) >> 1);
                bf16x8 bfr = *(const bf16x8*)&Ks[off];
                S[n] = MFMA16(a, bfr, S[n]);
            }
        }

        // online softmax over this lane's rows 4g+r
        float pm[4];
        #pragma unroll
        for (int r = 0; r < 4; ++r)
            pm[r] = fmaxf(fmaxf(S[0][r], S[1][r]), fmaxf(S[2][r], S[3][r]));
        #pragma unroll
        for (int off = 1; off < 16; off <<= 1) {
            #pragma unroll
            for (int r = 0; r < 4; ++r)
                pm[r] = fmaxf(pm[r], __shfl_xor(pm[r], off));
        }
        float al[4], psum[4];
        #pragma unroll
        for (int r = 0; r < 4; ++r) {
            float nm = fmaxf(mr[r], pm[r]);
            al[r]   = __expf(mr[r] - nm);
            mr[r]   = nm;
            lr[r]  *= al[r];
            psum[r] = 0.f;
        }
        #pragma unroll
        for (int n = 0; n < 4; ++n) {
            #pragma unroll
            for (int r = 0; r < 4; ++r) {
                float p = __expf(S[n][r] - mr[r]);
                psum[r] += p;
                int row = 4 * g + r;
                int off = wv * 1024 + row * 64 + (((32 * n + 2 * ln) ^ ((row & 7) << 4)) >> 1);
                Ps[off] = f2bf(p);
            }
        }
        #pragma unroll
        for (int off = 1; off < 16; off <<= 1) {
            #pragma unroll
            for (int r = 0; r < 4; ++r)
                psum[r] += __shfl_xor(psum[r], off);
        }
        #pragma unroll
        for (int r = 0; r < 4; ++r) lr[r] += psum[r];

        __syncthreads();   // P visible (also orders P write->read within wave)

        // O = diag(alpha) O + P V
        #pragma unroll
        for (int n = 0; n < 4; ++n) {
            #pragma unroll
            for (int r = 0; r < 4; ++r) O[n][r] *= al[r];
        }
        #pragma unroll
        for (int kk = 0; kk < 2; ++kk) {
            int aoff = wv * 1024 + ln * 64 + (((64 * kk + 16 * g) ^ ((ln & 7) << 4)) >> 1);
            bf16x8 pa = *(const bf16x8*)&Ps[aoff];
            #pragma unroll
            for (int n = 0; n < 4; ++n) {
                int vrow = 16 * n + ln;
                int voff = vrow * 64 + (((64 * kk + 16 * g) ^ ((vrow & 7) << 4)) >> 1);
                bf16x8 vb = *(const bf16x8*)&Vs[voff];
                O[n] = MFMA16(pa, vb, O[n]);
            }
        }
    }

    // epilogue: normalize and write fp32 ao [B][L][D]
    const int b = bh >> 4, h = bh & 15;
    #pragma unroll
    for (int r = 0; r < 4; ++r) {
        float inv = 1.0f / lr[r];
        int ql = q0 + 4 * g + r;
        float* dst = ao + ((size_t)(b * L_ + ql)) * D_ + h * 64;
        #pragma unroll
        for (int n = 0; n < 4; ++n)
            dst[16 * n + ln] = O[n][r] * inv;
    }
}

// ---------------------------------------------------------------------------
extern "C" void kernel_launch(void* const* d_in, const int* in_sizes, int n_in,
                              void* d_out, int out_size, void* d_ws, size_t ws_size,
                              hipStream_t stream)
{
    const float* x    = (const float*)d_in[0];
    const float* Wqkv = (const float*)d_in[1];
    const float* Wo   = (const float*)d_in[2];
    float* out = (float*)d_out;

    const size_t NQ = (size_t)B_ * H_ * L_ * DH_;          // 4M elements
    float* qf = (float*)d_ws;                              // [0,16MB)  fp32 Q
    float* kf = qf + NQ;                                   // [16,32MB) fp32 K
    float* vf = kf + NQ;                                   // [32,48MB) fp32 V
    ushort_t* qbp = (ushort_t*)((char*)d_ws + (size_t)48 * 1024 * 1024); // [48,56)
    ushort_t* kbp = (ushort_t*)((char*)d_ws + (size_t)56 * 1024 * 1024); // [56,64)
    ushort_t* vtp = (ushort_t*)d_ws;       // [0,8MB)  aliases qf (dead after rope)
    float*    aop = kf;                    // [16,32MB) aliases kf (dead after rope)

    // 1) QKV projection (fp32) with scatter to [B][H][L][DH]
    sgemm128<N1_, 1><<<dim3(N1_ / 128, M_ / 128), 256, 0, stream>>>(x, Wqkv, qf, kf, vf);
    // 2) RoPE -> bf16 (Q pre-scaled by 1/8)
    rope_bf16<<<(B_ * H_ * L_ * 32) / 256, 256, 0, stream>>>(qf, kf, qbp, kbp);
    // 3) V transpose -> bf16 [bh][64][L]
    transpose_v<<<dim3(B_ * H_, L_ / 64), 256, 0, stream>>>(vf, vtp);
    // 4) MFMA flash attention -> fp32 ao [B][L][D]
    attn_mfma<<<dim3(B_ * H_, L_ / 64), 256, 0, stream>>>(qbp, kbp, vtp, aop);
    // 5) output projection (fp32)
    sgemm128<D_, 0><<<dim3(D_ / 128, M_ / 128), 256, 0, stream>>>(aop, Wo, out, nullptr, nullptr);
}

// Round 3
// 199.705 us; speedup vs baseline: 5.5391x; 2.7452x over previous
//
#include <hip/hip_runtime.h>
#include <hip/hip_bf16.h>

#define B_  2
#define L_  2048
#define D_  1024
#define H_  16
#define DH_ 64
#define M_  (B_*L_)     // 4096
#define N1_ (3*D_)      // 3072

typedef __bf16 bf16x8 __attribute__((ext_vector_type(8)));
typedef float  f32x4  __attribute__((ext_vector_type(4)));
typedef unsigned short ushort_t;
typedef unsigned short ushort8_t __attribute__((ext_vector_type(8)));

#define MFMA16(a,b,c) __builtin_amdgcn_mfma_f32_16x16x32_bf16((a),(b),(c),0,0,0)

__device__ __forceinline__ float4 ld4(const float* p) { return *(const float4*)p; }

__device__ __forceinline__ ushort_t f2bf(float f) {
    union { float f; unsigned int u; } v; v.f = f;
    unsigned int r = (v.u + 0x7FFFu + ((v.u >> 16) & 1u)) >> 16;
    return (ushort_t)r;
}
__device__ __forceinline__ float bf2f(ushort_t u) {
    union { unsigned int u; float f; } v; v.u = ((unsigned int)u) << 16;
    return v.f;
}
// async global->LDS, 16B per lane; LDS dest = wave-uniform base + lane*16
__device__ __forceinline__ void gload16(const ushort_t* g, ushort_t* l) {
    __builtin_amdgcn_global_load_lds(
        (const __attribute__((address_space(1))) unsigned int*)g,
        (__attribute__((address_space(3))) unsigned int*)l, 16, 0, 0);
}

// ---------------------------------------------------------------------------
// x fp32 -> bf16, elementwise, 8/thread
// ---------------------------------------------------------------------------
__global__ __launch_bounds__(256)
void convert_x(const float* __restrict__ in, ushort_t* __restrict__ out)
{
    int i = (blockIdx.x * 256 + threadIdx.x) * 8;
    float4 a = ld4(in + i), b = ld4(in + i + 4);
    ushort8_t o;
    o[0] = f2bf(a.x); o[1] = f2bf(a.y); o[2] = f2bf(a.z); o[3] = f2bf(a.w);
    o[4] = f2bf(b.x); o[5] = f2bf(b.y); o[6] = f2bf(b.z); o[7] = f2bf(b.w);
    *(ushort8_t*)(out + i) = o;
}

// ---------------------------------------------------------------------------
// W fp32 [1024][N] -> bf16 W^T [N][1024], 64x64 LDS tiles
// ---------------------------------------------------------------------------
template<int N>
__global__ __launch_bounds__(256)
void transpose_w(const float* __restrict__ in, ushort_t* __restrict__ out)
{
    __shared__ float vs[64][65];
    const int nt = blockIdx.x, kt = blockIdx.y, t = threadIdx.x;
    #pragma unroll
    for (int i = 0; i < 4; ++i) {
        int idx = t + 256 * i;
        int row = idx >> 4, c4 = idx & 15;
        float4 x4 = ld4(in + (size_t)(kt * 64 + row) * N + nt * 64 + c4 * 4);
        vs[row][c4*4+0] = x4.x; vs[row][c4*4+1] = x4.y;
        vs[row][c4*4+2] = x4.z; vs[row][c4*4+3] = x4.w;
    }
    __syncthreads();
    #pragma unroll
    for (int i = 0; i < 16; ++i) {
        int idx = t + 256 * i;
        int nc = idx >> 6, kc = idx & 63;
        out[(size_t)(nt * 64 + nc) * 1024 + kt * 64 + kc] = f2bf(vs[kc][nc]);
    }
}

// ---------------------------------------------------------------------------
// bf16 MFMA GEMM, m97 structure: 128x128 tile, BK=64, 4 waves 2x2 (64x64 each),
// global_load_lds 16B staging with both-sides XOR chunk swizzle.
// A [M][1024] bf16 row-major, Bt [N][1024] bf16 row-major (= B^T).
// EPI 0: fp32 C [M][1024].  EPI 1: QKV scatter -> bf16 [bh][L][64] x3.
// Fragment layouts (HW-verified by round-2 attn refcheck):
//   A: lane holds A[ln][32kk+8g+j]  B: lane holds Bt[ln][32kk+8g+j]
//   D: lane reg r -> C[4g+r][ln]
// ---------------------------------------------------------------------------
template<int EPI>
__global__ __launch_bounds__(256)
void bgemm(const ushort_t* __restrict__ A, const ushort_t* __restrict__ Bt,
           float* __restrict__ Cf,
           ushort_t* __restrict__ Qo, ushort_t* __restrict__ Ko, ushort_t* __restrict__ Vo)
{
    constexpr int K = 1024;
    __shared__ ushort_t As[128 * 64];
    __shared__ ushort_t Bs[128 * 64];
    const int t  = threadIdx.x;
    const int l  = t & 63, w = t >> 6;
    const int g  = l >> 4, ln = l & 15;
    const int wr = w >> 1, wc = w & 1;
    const int m0 = blockIdx.y * 128, n0 = blockIdx.x * 128;

    // staging: issue i covers tile rows i*32 + w*8 + (l>>3); lane's 16B chunk:
    // phys = l&7, logical = phys ^ (row&7) = (l&7)^(l>>3)
    const int srow = w * 8 + (l >> 3);
    const int sch  = (l & 7) ^ (l >> 3);
    const ushort_t* Ag = A  + ((size_t)(m0 + srow)) * K + sch * 8;
    const ushort_t* Bg = Bt + ((size_t)(n0 + srow)) * K + sch * 8;

    f32x4 acc[4][4];
    #pragma unroll
    for (int mi = 0; mi < 4; ++mi)
        #pragma unroll
        for (int nj = 0; nj < 4; ++nj) acc[mi][nj] = f32x4{0.f, 0.f, 0.f, 0.f};

    for (int kt = 0; kt < K / 64; ++kt) {
        #pragma unroll
        for (int i = 0; i < 4; ++i)
            gload16(Ag + (size_t)i * 32 * K + kt * 64, &As[i * 2048 + w * 512]);
        #pragma unroll
        for (int i = 0; i < 4; ++i)
            gload16(Bg + (size_t)i * 32 * K + kt * 64, &Bs[i * 2048 + w * 512]);
        __syncthreads();   // compiler drains vmcnt(0) before s_barrier

        #pragma unroll
        for (int kk = 0; kk < 2; ++kk) {
            bf16x8 af[4], bfv[4];
            #pragma unroll
            for (int mi = 0; mi < 4; ++mi) {
                int row  = 64 * wr + 16 * mi + ln;
                int phys = (4 * kk + g) ^ (ln & 7);
                af[mi] = *(const bf16x8*)&As[row * 64 + phys * 8];
            }
            #pragma unroll
            for (int nj = 0; nj < 4; ++nj) {
                int row  = 64 * wc + 16 * nj + ln;
                int phys = (4 * kk + g) ^ (ln & 7);
                bfv[nj] = *(const bf16x8*)&Bs[row * 64 + phys * 8];
            }
            #pragma unroll
            for (int mi = 0; mi < 4; ++mi)
                #pragma unroll
                for (int nj = 0; nj < 4; ++nj)
                    acc[mi][nj] = MFMA16(af[mi], bfv[nj], acc[mi][nj]);
        }
        __syncthreads();   // LDS reuse
    }

    if (EPI == 0) {
        #pragma unroll
        for (int mi = 0; mi < 4; ++mi) {
            #pragma unroll
            for (int nj = 0; nj < 4; ++nj) {
                int n = n0 + 64 * wc + 16 * nj + ln;
                #pragma unroll
                for (int r = 0; r < 4; ++r) {
                    int m = m0 + 64 * wr + 16 * mi + 4 * g + r;
                    Cf[(size_t)m * D_ + n] = acc[mi][nj][r];
                }
            }
        }
    } else {
        #pragma unroll
        for (int mi = 0; mi < 4; ++mi) {
            #pragma unroll
            for (int nj = 0; nj < 4; ++nj) {
                int n = n0 + 64 * wc + 16 * nj + ln;
                int which = n >> 10;
                int h  = (n >> 6) & (H_ - 1);
                int dh = n & (DH_ - 1);
                ushort_t* base = (which == 0) ? Qo : ((which == 1) ? Ko : Vo);
                #pragma unroll
                for (int r = 0; r < 4; ++r) {
                    int m = m0 + 64 * wr + 16 * mi + 4 * g + r;
                    int b = m >> 11, ll = m & (L_ - 1);
                    base[((size_t)(b * H_ + h) * L_ + ll) * DH_ + dh] = f2bf(acc[mi][nj][r]);
                }
            }
        }
    }
}

// ---------------------------------------------------------------------------
// RoPE bf16 -> bf16, Q pre-scaled by 1/8. 4 pairs per thread.
// ---------------------------------------------------------------------------
__global__ __launch_bounds__(256)
void rope_bf16(const ushort_t* __restrict__ q, const ushort_t* __restrict__ k,
               ushort_t* __restrict__ qo, ushort_t* __restrict__ ko)
{
    int gid = blockIdx.x * 256 + threadIdx.x;       // B*H*L*8 threads
    int j4  = (gid & 7) * 4;
    int l   = (gid >> 3) & (L_ - 1);
    int bh  = gid >> 14;
    size_t base = ((size_t)bh * L_ + l) * DH_;

    ushort_t a1[4], a2[4], b1[4], b2[4], o1[4], o2[4], p1[4], p2[4];
    *(ushort4*)a1 = *(const ushort4*)(q + base + j4);
    *(ushort4*)a2 = *(const ushort4*)(q + base + j4 + 32);
    *(ushort4*)b1 = *(const ushort4*)(k + base + j4);
    *(ushort4*)b2 = *(const ushort4*)(k + base + j4 + 32);
    #pragma unroll
    for (int jj = 0; jj < 4; ++jj) {
        int j = j4 + jj;
        float inv = powf(10000.0f, -(float)j * (1.0f / 32.0f));
        float s, c;
        sincosf((float)l * inv, &s, &c);
        float q1 = bf2f(a1[jj]), q2 = bf2f(a2[jj]);
        o1[jj] = f2bf((q1 * c - q2 * s) * 0.125f);
        o2[jj] = f2bf((q2 * c + q1 * s) * 0.125f);
        float k1 = bf2f(b1[jj]), k2 = bf2f(b2[jj]);
        p1[jj] = f2bf(k1 * c - k2 * s);
        p2[jj] = f2bf(k2 * c + k1 * s);
    }
    *(ushort4*)(qo + base + j4)      = *(ushort4*)o1;
    *(ushort4*)(qo + base + j4 + 32) = *(ushort4*)o2;
    *(ushort4*)(ko + base + j4)      = *(ushort4*)p1;
    *(ushort4*)(ko + base + j4 + 32) = *(ushort4*)p2;
}

// ---------------------------------------------------------------------------
// V bf16 [bh][L][64] -> vt bf16 [bh][64][L]
// ---------------------------------------------------------------------------
__global__ __launch_bounds__(256)
void transpose_v(const ushort_t* __restrict__ v, ushort_t* __restrict__ vt)
{
    __shared__ ushort_t vs[64][68];
    const int bh = blockIdx.x, lt = blockIdx.y, t = threadIdx.x;
    #pragma unroll
    for (int i = 0; i < 2; ++i) {
        int idx = t + 256 * i;          // 512 chunks of 8
        int row = idx >> 3, c8 = idx & 7;
        ushort8_t x = *(const ushort8_t*)(v + ((size_t)(bh * L_ + lt * 64 + row)) * 64 + c8 * 8);
        #pragma unroll
        for (int jj = 0; jj < 8; ++jj) vs[row][c8 * 8 + jj] = x[jj];
    }
    __syncthreads();
    #pragma unroll
    for (int i = 0; i < 16; ++i) {
        int idx = t + 256 * i;
        int d = idx >> 6, lc = idx & 63;
        vt[((size_t)(bh * 64 + d)) * L_ + lt * 64 + lc] = vs[lc][d];
    }
}

// ---------------------------------------------------------------------------
// Flash attention, bf16 MFMA (unchanged structure from round 2; ao now bf16)
// ---------------------------------------------------------------------------
__global__ __launch_bounds__(256)
void attn_mfma(const ushort_t* __restrict__ qb, const ushort_t* __restrict__ kb,
               const ushort_t* __restrict__ vt, ushort_t* __restrict__ ao)
{
    __shared__ ushort_t Ks[64 * 64];
    __shared__ ushort_t Vs[64 * 64];
    __shared__ ushort_t Ps[4 * 16 * 64];

    const int t    = threadIdx.x;
    const int lane = t & 63, wv = t >> 6;
    const int g    = lane >> 4, ln = lane & 15;
    const int bh   = blockIdx.x;
    const int q0   = blockIdx.y * 64 + wv * 16;

    const ushort_t* qp = qb + ((size_t)bh * L_ + q0 + ln) * DH_;
    bf16x8 qf0 = *(const bf16x8*)(qp + 8 * g);
    bf16x8 qf1 = *(const bf16x8*)(qp + 32 + 8 * g);

    const ushort_t* kp = kb + (size_t)bh * L_ * DH_;
    const ushort_t* vp = vt + (size_t)bh * DH_ * L_;

    f32x4 O[4];
    #pragma unroll
    for (int n = 0; n < 4; ++n) O[n] = f32x4{0.f, 0.f, 0.f, 0.f};
    float mr[4], lr[4];
    #pragma unroll
    for (int r = 0; r < 4; ++r) { mr[r] = -INFINITY; lr[r] = 0.f; }

    for (int kt = 0; kt < L_ / 64; ++kt) {
        __syncthreads();
        #pragma unroll
        for (int it = 0; it < 2; ++it) {
            int idx = t + it * 256;
            int row = idx >> 3, ch = idx & 7;
            int dst = row * 64 + ((((ch * 16) ^ ((row & 7) << 4))) >> 1);
            *(bf16x8*)&Ks[dst] = *(const bf16x8*)(kp + (size_t)(kt * 64 + row) * 64 + ch * 8);
            *(bf16x8*)&Vs[dst] = *(const bf16x8*)(vp + (size_t)row * L_ + kt * 64 + ch * 8);
        }
        __syncthreads();

        f32x4 S[4];
        #pragma unroll
        for (int n = 0; n < 4; ++n) S[n] = f32x4{0.f, 0.f, 0.f, 0.f};
        #pragma unroll
        for (int kk = 0; kk < 2; ++kk) {
            bf16x8 a = kk ? qf1 : qf0;
            #pragma unroll
            for (int n = 0; n < 4; ++n) {
                int row = 16 * n + ln;
                int off = row * 64 + (((64 * kk + 16 * g) ^ ((row & 7) << 4)) >> 1);
                bf16x8 bfr = *(const bf16x8*)&Ks[off];
                S[n] = MFMA16(a, bfr, S[n]);
            }
        }

        float pm[4];
        #pragma unroll
        for (int r = 0; r < 4; ++r)
            pm[r] = fmaxf(fmaxf(S[0][r], S[1][r]), fmaxf(S[2][r], S[3][r]));
        #pragma unroll
        for (int off = 1; off < 16; off <<= 1) {
            #pragma unroll
            for (int r = 0; r < 4; ++r)
                pm[r] = fmaxf(pm[r], __shfl_xor(pm[r], off));
        }
        float al[4], psum[4];
        #pragma unroll
        for (int r = 0; r < 4; ++r) {
            float nm = fmaxf(mr[r], pm[r]);
            al[r]   = __expf(mr[r] - nm);
            mr[r]   = nm;
            lr[r]  *= al[r];
            psum[r] = 0.f;
        }
        #pragma unroll
        for (int n = 0; n < 4; ++n) {
            #pragma unroll
            for (int r = 0; r < 4; ++r) {
                float p = __expf(S[n][r] - mr[r]);
                psum[r] += p;
                int row = 4 * g + r;
                int off = wv * 1024 + row * 64 + (((32 * n + 2 * ln) ^ ((row & 7) << 4)) >> 1);
                Ps[off] = f2bf(p);
            }
        }
        #pragma unroll
        for (int off = 1; off < 16; off <<= 1) {
            #pragma unroll
            for (int r = 0; r < 4; ++r)
                psum[r] += __shfl_xor(psum[r], off);
        }
        #pragma unroll
        for (int r = 0; r < 4; ++r) lr[r] += psum[r];

        __syncthreads();

        #pragma unroll
        for (int n = 0; n < 4; ++n) {
            #pragma unroll
            for (int r = 0; r < 4; ++r) O[n][r] *= al[r];
        }
        #pragma unroll
        for (int kk = 0; kk < 2; ++kk) {
            int aoff = wv * 1024 + ln * 64 + (((64 * kk + 16 * g) ^ ((ln & 7) << 4)) >> 1);
            bf16x8 pa = *(const bf16x8*)&Ps[aoff];
            #pragma unroll
            for (int n = 0; n < 4; ++n) {
                int vrow = 16 * n + ln;
                int voff = vrow * 64 + (((64 * kk + 16 * g) ^ ((vrow & 7) << 4)) >> 1);
                bf16x8 vb = *(const bf16x8*)&Vs[voff];
                O[n] = MFMA16(pa, vb, O[n]);
            }
        }
    }

    const int b = bh >> 4, h = bh & 15;
    #pragma unroll
    for (int r = 0; r < 4; ++r) {
        float inv = 1.0f / lr[r];
        int ql = q0 + 4 * g + r;
        ushort_t* dst = ao + ((size_t)(b * L_ + ql)) * D_ + h * 64;
        #pragma unroll
        for (int n = 0; n < 4; ++n)
            dst[16 * n + ln] = f2bf(O[n][r] * inv);
    }
}

// ---------------------------------------------------------------------------
extern "C" void kernel_launch(void* const* d_in, const int* in_sizes, int n_in,
                              void* d_out, int out_size, void* d_ws, size_t ws_size,
                              hipStream_t stream)
{
    const float* x    = (const float*)d_in[0];
    const float* Wqkv = (const float*)d_in[1];
    const float* Wo   = (const float*)d_in[2];
    float* out = (float*)d_out;

    char* ws = (char*)d_ws;                               // 64 MB layout:
    ushort_t* xb  = (ushort_t*)(ws);                      // [0,8M)   x bf16; later ao
    ushort_t* wqt = (ushort_t*)(ws + ((size_t) 8 << 20)); // [8,14M)  Wqkv^T bf16
    ushort_t* wot = (ushort_t*)(ws + ((size_t)14 << 20)); // [14,16M) Wo^T bf16
    ushort_t* qB  = (ushort_t*)(ws + ((size_t)16 << 20)); // [16,24M) q pre-rope
    ushort_t* kB  = (ushort_t*)(ws + ((size_t)24 << 20)); // [24,32M) k pre-rope
    ushort_t* vB  = (ushort_t*)(ws + ((size_t)32 << 20)); // [32,40M) v
    ushort_t* qR  = (ushort_t*)(ws + ((size_t)40 << 20)); // [40,48M) q rope'd
    ushort_t* kR  = (ushort_t*)(ws + ((size_t)48 << 20)); // [48,56M) k rope'd
    ushort_t* vt  = (ushort_t*)(ws + ((size_t)56 << 20)); // [56,64M) v^T
    ushort_t* ao  = xb;                                   // alias (xb dead post-gemm)

    convert_x<<<(M_ * D_) / (8 * 256), 256, 0, stream>>>(x, xb);
    transpose_w<N1_><<<dim3(N1_ / 64, 16), 256, 0, stream>>>(Wqkv, wqt);
    transpose_w<D_ ><<<dim3(D_  / 64, 16), 256, 0, stream>>>(Wo, wot);

    bgemm<1><<<dim3(N1_ / 128, M_ / 128), 256, 0, stream>>>(xb, wqt, nullptr, qB, kB, vB);
    rope_bf16<<<(B_ * H_ * L_ * 8) / 256, 256, 0, stream>>>(qB, kB, qR, kR);
    transpose_v<<<dim3(B_ * H_, L_ / 64), 256, 0, stream>>>(vB, vt);
    attn_mfma<<<dim3(B_ * H_, L_ / 64), 256, 0, stream>>>(qR, kR, vt, ao);
    bgemm<0><<<dim3(D_ / 128, M_ / 128), 256, 0, stream>>>(ao, wot, out, nullptr, nullptr, nullptr);
}

// Round 5
// 196.593 us; speedup vs baseline: 5.6268x; 1.0158x over previous
//
#include <hip/hip_runtime.h>
#include <hip/hip_bf16.h>

#define B_  2
#define L_  2048
#define D_  1024
#define H_  16
#define DH_ 64
#define M_  (B_*L_)     // 4096
#define N1_ (3*D_)      // 3072

typedef __bf16 bf16x8 __attribute__((ext_vector_type(8)));
typedef float  f32x4  __attribute__((ext_vector_type(4)));
typedef unsigned short ushort_t;
typedef unsigned short ushort8_t __attribute__((ext_vector_type(8)));

#define MFMA16(a,b,c) __builtin_amdgcn_mfma_f32_16x16x32_bf16((a),(b),(c),0,0,0)

__device__ __forceinline__ float4 ld4(const float* p) { return *(const float4*)p; }

__device__ __forceinline__ ushort_t f2bf(float f) {
    union { float f; unsigned int u; } v; v.f = f;
    unsigned int r = (v.u + 0x7FFFu + ((v.u >> 16) & 1u)) >> 16;
    return (ushort_t)r;
}
__device__ __forceinline__ float bf2f(ushort_t u) {
    union { unsigned int u; float f; } v; v.u = ((unsigned int)u) << 16;
    return v.f;
}
// v_exp_f32 computes 2^x
__device__ __forceinline__ float exp2_(float x) {
    float r; asm("v_exp_f32 %0, %1" : "=v"(r) : "v"(x)); return r;
}
// async global->LDS, 16B per lane; LDS dest = wave-uniform base + lane*16
__device__ __forceinline__ void gload16(const ushort_t* g, ushort_t* l) {
    __builtin_amdgcn_global_load_lds(
        (const __attribute__((address_space(1))) unsigned int*)g,
        (__attribute__((address_space(3))) unsigned int*)l, 16, 0, 0);
}

// ---------------------------------------------------------------------------
// x fp32 -> bf16, elementwise, 8/thread
// ---------------------------------------------------------------------------
__global__ __launch_bounds__(256)
void convert_x(const float* __restrict__ in, ushort_t* __restrict__ out)
{
    int i = (blockIdx.x * 256 + threadIdx.x) * 8;
    float4 a = ld4(in + i), b = ld4(in + i + 4);
    ushort8_t o;
    o[0] = f2bf(a.x); o[1] = f2bf(a.y); o[2] = f2bf(a.z); o[3] = f2bf(a.w);
    o[4] = f2bf(b.x); o[5] = f2bf(b.y); o[6] = f2bf(b.z); o[7] = f2bf(b.w);
    *(ushort8_t*)(out + i) = o;
}

// ---------------------------------------------------------------------------
// W fp32 [1024][N] -> bf16 W^T [N][1024], 64x64 LDS tiles
// ---------------------------------------------------------------------------
template<int N>
__global__ __launch_bounds__(256)
void transpose_w(const float* __restrict__ in, ushort_t* __restrict__ out)
{
    __shared__ float vs[64][65];
    const int nt = blockIdx.x, kt = blockIdx.y, t = threadIdx.x;
    #pragma unroll
    for (int i = 0; i < 4; ++i) {
        int idx = t + 256 * i;
        int row = idx >> 4, c4 = idx & 15;
        float4 x4 = ld4(in + (size_t)(kt * 64 + row) * N + nt * 64 + c4 * 4);
        vs[row][c4*4+0] = x4.x; vs[row][c4*4+1] = x4.y;
        vs[row][c4*4+2] = x4.z; vs[row][c4*4+3] = x4.w;
    }
    __syncthreads();
    #pragma unroll
    for (int i = 0; i < 16; ++i) {
        int idx = t + 256 * i;
        int nc = idx >> 6, kc = idx & 63;
        out[(size_t)(nt * 64 + nc) * 1024 + kt * 64 + kc] = f2bf(vs[kc][nc]);
    }
}

// ---------------------------------------------------------------------------
// bf16 MFMA GEMM, m97 structure (unchanged from round 3, known-correct).
// ---------------------------------------------------------------------------
template<int EPI>
__global__ __launch_bounds__(256)
void bgemm(const ushort_t* __restrict__ A, const ushort_t* __restrict__ Bt,
           float* __restrict__ Cf,
           ushort_t* __restrict__ Qo, ushort_t* __restrict__ Ko, ushort_t* __restrict__ Vo)
{
    constexpr int K = 1024;
    __shared__ ushort_t As[128 * 64];
    __shared__ ushort_t Bs[128 * 64];
    const int t  = threadIdx.x;
    const int l  = t & 63, w = t >> 6;
    const int g  = l >> 4, ln = l & 15;
    const int wr = w >> 1, wc = w & 1;
    const int m0 = blockIdx.y * 128, n0 = blockIdx.x * 128;

    const int srow = w * 8 + (l >> 3);
    const int sch  = (l & 7) ^ (l >> 3);
    const ushort_t* Ag = A  + ((size_t)(m0 + srow)) * K + sch * 8;
    const ushort_t* Bg = Bt + ((size_t)(n0 + srow)) * K + sch * 8;

    f32x4 acc[4][4];
    #pragma unroll
    for (int mi = 0; mi < 4; ++mi)
        #pragma unroll
        for (int nj = 0; nj < 4; ++nj) acc[mi][nj] = f32x4{0.f, 0.f, 0.f, 0.f};

    for (int kt = 0; kt < K / 64; ++kt) {
        #pragma unroll
        for (int i = 0; i < 4; ++i)
            gload16(Ag + (size_t)i * 32 * K + kt * 64, &As[i * 2048 + w * 512]);
        #pragma unroll
        for (int i = 0; i < 4; ++i)
            gload16(Bg + (size_t)i * 32 * K + kt * 64, &Bs[i * 2048 + w * 512]);
        __syncthreads();

        #pragma unroll
        for (int kk = 0; kk < 2; ++kk) {
            bf16x8 af[4], bfv[4];
            #pragma unroll
            for (int mi = 0; mi < 4; ++mi) {
                int row  = 64 * wr + 16 * mi + ln;
                int phys = (4 * kk + g) ^ (ln & 7);
                af[mi] = *(const bf16x8*)&As[row * 64 + phys * 8];
            }
            #pragma unroll
            for (int nj = 0; nj < 4; ++nj) {
                int row  = 64 * wc + 16 * nj + ln;
                int phys = (4 * kk + g) ^ (ln & 7);
                bfv[nj] = *(const bf16x8*)&Bs[row * 64 + phys * 8];
            }
            #pragma unroll
            for (int mi = 0; mi < 4; ++mi)
                #pragma unroll
                for (int nj = 0; nj < 4; ++nj)
                    acc[mi][nj] = MFMA16(af[mi], bfv[nj], acc[mi][nj]);
        }
        __syncthreads();
    }

    if (EPI == 0) {
        #pragma unroll
        for (int mi = 0; mi < 4; ++mi) {
            #pragma unroll
            for (int nj = 0; nj < 4; ++nj) {
                int n = n0 + 64 * wc + 16 * nj + ln;
                #pragma unroll
                for (int r = 0; r < 4; ++r) {
                    int m = m0 + 64 * wr + 16 * mi + 4 * g + r;
                    Cf[(size_t)m * D_ + n] = acc[mi][nj][r];
                }
            }
        }
    } else {
        #pragma unroll
        for (int mi = 0; mi < 4; ++mi) {
            #pragma unroll
            for (int nj = 0; nj < 4; ++nj) {
                int n = n0 + 64 * wc + 16 * nj + ln;
                int which = n >> 10;
                int h  = (n >> 6) & (H_ - 1);
                int dh = n & (DH_ - 1);
                ushort_t* base = (which == 0) ? Qo : ((which == 1) ? Ko : Vo);
                #pragma unroll
                for (int r = 0; r < 4; ++r) {
                    int m = m0 + 64 * wr + 16 * mi + 4 * g + r;
                    int b = m >> 11, ll = m & (L_ - 1);
                    base[((size_t)(b * H_ + h) * L_ + ll) * DH_ + dh] = f2bf(acc[mi][nj][r]);
                }
            }
        }
    }
}

// ---------------------------------------------------------------------------
// RoPE bf16 -> bf16. Q pre-scaled by (1/8)*log2(e) so softmax can use 2^x.
// ---------------------------------------------------------------------------
#define QSCALE (0.125f * 1.44269504088896340736f)
__global__ __launch_bounds__(256)
void rope_bf16(const ushort_t* __restrict__ q, const ushort_t* __restrict__ k,
               ushort_t* __restrict__ qo, ushort_t* __restrict__ ko)
{
    int gid = blockIdx.x * 256 + threadIdx.x;       // B*H*L*8 threads
    int j4  = (gid & 7) * 4;
    int l   = (gid >> 3) & (L_ - 1);
    int bh  = gid >> 14;
    size_t base = ((size_t)bh * L_ + l) * DH_;

    ushort_t a1[4], a2[4], b1[4], b2[4], o1[4], o2[4], p1[4], p2[4];
    *(ushort4*)a1 = *(const ushort4*)(q + base + j4);
    *(ushort4*)a2 = *(const ushort4*)(q + base + j4 + 32);
    *(ushort4*)b1 = *(const ushort4*)(k + base + j4);
    *(ushort4*)b2 = *(const ushort4*)(k + base + j4 + 32);
    #pragma unroll
    for (int jj = 0; jj < 4; ++jj) {
        int j = j4 + jj;
        float inv = powf(10000.0f, -(float)j * (1.0f / 32.0f));
        float s, c;
        sincosf((float)l * inv, &s, &c);
        float q1 = bf2f(a1[jj]), q2 = bf2f(a2[jj]);
        o1[jj] = f2bf((q1 * c - q2 * s) * QSCALE);
        o2[jj] = f2bf((q2 * c + q1 * s) * QSCALE);
        float k1 = bf2f(b1[jj]), k2 = bf2f(b2[jj]);
        p1[jj] = f2bf(k1 * c - k2 * s);
        p2[jj] = f2bf(k2 * c + k1 * s);
    }
    *(ushort4*)(qo + base + j4)      = *(ushort4*)o1;
    *(ushort4*)(qo + base + j4 + 32) = *(ushort4*)o2;
    *(ushort4*)(ko + base + j4)      = *(ushort4*)p1;
    *(ushort4*)(ko + base + j4 + 32) = *(ushort4*)p2;
}

// ---------------------------------------------------------------------------
// V bf16 [bh][L][64] -> vt bf16 [bh][64][L]
// ---------------------------------------------------------------------------
__global__ __launch_bounds__(256)
void transpose_v(const ushort_t* __restrict__ v, ushort_t* __restrict__ vt)
{
    __shared__ ushort_t vs[64][68];
    const int bh = blockIdx.x, lt = blockIdx.y, t = threadIdx.x;
    #pragma unroll
    for (int i = 0; i < 2; ++i) {
        int idx = t + 256 * i;
        int row = idx >> 3, c8 = idx & 7;
        ushort8_t x = *(const ushort8_t*)(v + ((size_t)(bh * L_ + lt * 64 + row)) * 64 + c8 * 8);
        #pragma unroll
        for (int jj = 0; jj < 8; ++jj) vs[row][c8 * 8 + jj] = x[jj];
    }
    __syncthreads();
    #pragma unroll
    for (int i = 0; i < 16; ++i) {
        int idx = t + 256 * i;
        int d = idx >> 6, lc = idx & 63;
        vt[((size_t)(bh * 64 + d)) * L_ + lt * 64 + lc] = vs[lc][d];
    }
}

// ---------------------------------------------------------------------------
// Flash attention v3: double-buffered K/V via global_load_lds + counted
// vmcnt(4) + raw barriers + COMPILER FENCES after each barrier (R4 bug:
// raw s_barrier is not a compiler memory fence -> K/V ds_reads hoisted
// above the barrier read rows other waves had not finished staging).
// P path = round-3 proven scheme (wave-private swizzled LDS, scalar
// stores, swizzled bf16x8 reads; same-wave DS is in-order so no barrier).
// Layouts: A: lane holds A[ln][32kk+8g+j]; B: lane holds Bt[ln][32kk+8g+j];
//          D: lane reg r -> D[4g+r][ln]   (g=lane>>4, ln=lane&15)
// ---------------------------------------------------------------------------
__global__ __launch_bounds__(256)
void attn_mfma(const ushort_t* __restrict__ qb, const ushort_t* __restrict__ kb,
               const ushort_t* __restrict__ vt, ushort_t* __restrict__ ao)
{
    __shared__ ushort_t Ks[2][64 * 64];     // [key][d], swizzled chunks
    __shared__ ushort_t Vs[2][64 * 64];     // [d][key], swizzled chunks
    __shared__ ushort_t Ps[4][16 * 64];     // per-wave P [16 q][64 key], swizzled

    const int t    = threadIdx.x;
    const int lane = t & 63, wv = t >> 6;
    const int g    = lane >> 4, ln = lane & 15;
    const int bh   = blockIdx.x;
    const int q0   = blockIdx.y * 64 + wv * 16;

    // Q fragments straight from global: lane holds Q[q0+ln][32kk+8g+j]
    const ushort_t* qp = qb + ((size_t)bh * L_ + q0 + ln) * DH_;
    bf16x8 qf0 = *(const bf16x8*)(qp + 8 * g);
    bf16x8 qf1 = *(const bf16x8*)(qp + 32 + 8 * g);

    const ushort_t* kp = kb + (size_t)bh * L_ * DH_;
    const ushort_t* vp = vt + (size_t)bh * DH_ * L_;

    // staging geometry: lane covers row srow+8i, phys chunk l&7, source chunk sch
    const int srow = 16 * wv + (lane >> 3);
    const int sch  = (lane & 7) ^ (lane >> 3);

    f32x4 O[4];
    #pragma unroll
    for (int n = 0; n < 4; ++n) O[n] = f32x4{0.f, 0.f, 0.f, 0.f};
    float mr[4], lr[4];
    #pragma unroll
    for (int r = 0; r < 4; ++r) { mr[r] = -INFINITY; lr[r] = 0.f; }

    // prologue: tile 0 -> buf 0 (4 loads per wave)
    #pragma unroll
    for (int i = 0; i < 2; ++i) {
        gload16(kp + ((size_t)(srow + 8 * i)) * 64 + sch * 8,
                &Ks[0][(16 * wv + 8 * i) * 64]);
        gload16(vp + ((size_t)(srow + 8 * i)) * L_ + sch * 8,
                &Vs[0][(16 * wv + 8 * i) * 64]);
    }

    for (int kt = 0; kt < L_ / 64; ++kt) {
        const int cur = kt & 1, nxt = cur ^ 1;
        const int nk  = (kt < L_ / 64 - 1) ? kt + 1 : kt;   // clamp: redundant reload
        #pragma unroll
        for (int i = 0; i < 2; ++i) {
            gload16(kp + ((size_t)(nk * 64 + srow + 8 * i)) * 64 + sch * 8,
                    &Ks[nxt][(16 * wv + 8 * i) * 64]);
            gload16(vp + ((size_t)(srow + 8 * i)) * L_ + nk * 64 + sch * 8,
                    &Vs[nxt][(16 * wv + 8 * i) * 64]);
        }
        asm volatile("s_waitcnt vmcnt(4)" ::: "memory");  // my tile-kt loads landed
        __builtin_amdgcn_s_barrier();                      // landed for ALL waves
        asm volatile("" ::: "memory");   // fence: no LDS reads above the barrier

        const ushort_t* Kc = &Ks[cur][0];
        const ushort_t* Vc = &Vs[cur][0];

        // ---- QK^T ----
        f32x4 S[4];
        #pragma unroll
        for (int n = 0; n < 4; ++n) S[n] = f32x4{0.f, 0.f, 0.f, 0.f};
        bf16x8 kf[2][4];
        #pragma unroll
        for (int kk = 0; kk < 2; ++kk)
            #pragma unroll
            for (int n = 0; n < 4; ++n) {
                int row  = 16 * n + ln;
                int phys = (4 * kk + g) ^ (ln & 7);
                kf[kk][n] = *(const bf16x8*)&Kc[row * 64 + phys * 8];
            }
        __builtin_amdgcn_s_setprio(1);
        #pragma unroll
        for (int kk = 0; kk < 2; ++kk) {
            bf16x8 a = kk ? qf1 : qf0;
            #pragma unroll
            for (int n = 0; n < 4; ++n) S[n] = MFMA16(a, kf[kk][n], S[n]);
        }
        __builtin_amdgcn_s_setprio(0);

        // ---- online softmax (base-2 domain; scale folded into Q) ----
        float pm[4];
        #pragma unroll
        for (int r = 0; r < 4; ++r)
            pm[r] = fmaxf(fmaxf(S[0][r], S[1][r]), fmaxf(S[2][r], S[3][r]));
        #pragma unroll
        for (int off = 1; off < 16; off <<= 1) {
            #pragma unroll
            for (int r = 0; r < 4; ++r)
                pm[r] = fmaxf(pm[r], __shfl_xor(pm[r], off));
        }
        float al[4], psum[4];
        #pragma unroll
        for (int r = 0; r < 4; ++r) {
            float nm = fmaxf(mr[r], pm[r]);
            al[r]   = exp2_(mr[r] - nm);
            mr[r]   = nm;
            lr[r]  *= al[r];
            psum[r] = 0.f;
        }
        // P[q=4g+r][key=16n+ln] scalar stores, swizzled (round-3 proven path)
        #pragma unroll
        for (int n = 0; n < 4; ++n) {
            #pragma unroll
            for (int r = 0; r < 4; ++r) {
                float p = exp2_(S[n][r] - mr[r]);
                psum[r] += p;
                int row = 4 * g + r;
                int off = wv * 1024 + row * 64 + (((32 * n + 2 * ln) ^ ((row & 7) << 4)) >> 1);
                Ps[0][off] = f2bf(p);
            }
        }
        #pragma unroll
        for (int off = 1; off < 16; off <<= 1) {
            #pragma unroll
            for (int r = 0; r < 4; ++r)
                psum[r] += __shfl_xor(psum[r], off);
        }
        #pragma unroll
        for (int r = 0; r < 4; ++r) lr[r] += psum[r];

        // ---- PV (no barrier: P is wave-private, same-wave DS is in-order) ----
        #pragma unroll
        for (int n = 0; n < 4; ++n) {
            #pragma unroll
            for (int r = 0; r < 4; ++r) O[n][r] *= al[r];
        }
        #pragma unroll
        for (int kk = 0; kk < 2; ++kk) {
            int aoff = wv * 1024 + ln * 64 + (((64 * kk + 16 * g) ^ ((ln & 7) << 4)) >> 1);
            bf16x8 pa = *(const bf16x8*)&Ps[0][aoff];
            bf16x8 vf[4];
            #pragma unroll
            for (int n = 0; n < 4; ++n) {
                int vrow = 16 * n + ln;
                int voff = vrow * 64 + (((64 * kk + 16 * g) ^ ((vrow & 7) << 4)) >> 1);
                vf[n] = *(const bf16x8*)&Vc[voff];
            }
            __builtin_amdgcn_s_setprio(1);
            #pragma unroll
            for (int n = 0; n < 4; ++n) O[n] = MFMA16(pa, vf[n], O[n]);
            __builtin_amdgcn_s_setprio(0);
        }

        __builtin_amdgcn_s_barrier();    // all waves done reading buf[cur]
        asm volatile("" ::: "memory");   // fence: next staging stays below
    }
    asm volatile("s_waitcnt vmcnt(0)" ::: "memory");  // drain redundant tail loads

    // epilogue: normalize, write bf16 ao [B][L][D]
    const int b = bh >> 4, h = bh & 15;
    #pragma unroll
    for (int r = 0; r < 4; ++r) {
        float inv = 1.0f / lr[r];
        int ql = q0 + 4 * g + r;
        ushort_t* dst = ao + ((size_t)(b * L_ + ql)) * D_ + h * 64;
        #pragma unroll
        for (int n = 0; n < 4; ++n)
            dst[16 * n + ln] = f2bf(O[n][r] * inv);
    }
}

// ---------------------------------------------------------------------------
extern "C" void kernel_launch(void* const* d_in, const int* in_sizes, int n_in,
                              void* d_out, int out_size, void* d_ws, size_t ws_size,
                              hipStream_t stream)
{
    const float* x    = (const float*)d_in[0];
    const float* Wqkv = (const float*)d_in[1];
    const float* Wo   = (const float*)d_in[2];
    float* out = (float*)d_out;

    char* ws = (char*)d_ws;                               // 64 MB layout:
    ushort_t* xb  = (ushort_t*)(ws);                      // [0,8M)   x bf16; later ao
    ushort_t* wqt = (ushort_t*)(ws + ((size_t) 8 << 20)); // [8,14M)  Wqkv^T bf16
    ushort_t* wot = (ushort_t*)(ws + ((size_t)14 << 20)); // [14,16M) Wo^T bf16
    ushort_t* qB  = (ushort_t*)(ws + ((size_t)16 << 20)); // [16,24M) q pre-rope
    ushort_t* kB  = (ushort_t*)(ws + ((size_t)24 << 20)); // [24,32M) k pre-rope
    ushort_t* vB  = (ushort_t*)(ws + ((size_t)32 << 20)); // [32,40M) v
    ushort_t* qR  = (ushort_t*)(ws + ((size_t)40 << 20)); // [40,48M) q rope'd
    ushort_t* kR  = (ushort_t*)(ws + ((size_t)48 << 20)); // [48,56M) k rope'd
    ushort_t* vt  = (ushort_t*)(ws + ((size_t)56 << 20)); // [56,64M) v^T
    ushort_t* ao  = xb;                                   // alias (xb dead post-gemm)

    convert_x<<<(M_ * D_) / (8 * 256), 256, 0, stream>>>(x, xb);
    transpose_w<N1_><<<dim3(N1_ / 64, 16), 256, 0, stream>>>(Wqkv, wqt);
    transpose_w<D_ ><<<dim3(D_  / 64, 16), 256, 0, stream>>>(Wo, wot);

    bgemm<1><<<dim3(N1_ / 128, M_ / 128), 256, 0, stream>>>(xb, wqt, nullptr, qB, kB, vB);
    rope_bf16<<<(B_ * H_ * L_ * 8) / 256, 256, 0, stream>>>(qB, kB, qR, kR);
    transpose_v<<<dim3(B_ * H_, L_ / 64), 256, 0, stream>>>(vB, vt);
    attn_mfma<<<dim3(B_ * H_, L_ / 64), 256, 0, stream>>>(qR, kR, vt, ao);
    bgemm<0><<<dim3(D_ / 128, M_ / 128), 256, 0, stream>>>(ao, wot, out, nullptr, nullptr, nullptr);
}

// Round 6
// 156.993 us; speedup vs baseline: 7.0461x; 1.2522x over previous
//
#include <hip/hip_runtime.h>
#include <hip/hip_bf16.h>

#define B_  2
#define L_  2048
#define D_  1024
#define H_  16
#define DH_ 64
#define M_  (B_*L_)     // 4096
#define N1_ (3*D_)      // 3072

typedef __bf16 bf16x8 __attribute__((ext_vector_type(8)));
typedef float  f32x4  __attribute__((ext_vector_type(4)));
typedef unsigned short ushort_t;
typedef unsigned short ushort8_t __attribute__((ext_vector_type(8)));
typedef unsigned int   uintx2    __attribute__((ext_vector_type(2)));

#define MFMA16(a,b,c) __builtin_amdgcn_mfma_f32_16x16x32_bf16((a),(b),(c),0,0,0)

__device__ __forceinline__ float4 ld4(const float* p) { return *(const float4*)p; }

__device__ __forceinline__ ushort_t f2bf(float f) {
    union { float f; unsigned int u; } v; v.f = f;
    unsigned int r = (v.u + 0x7FFFu + ((v.u >> 16) & 1u)) >> 16;
    return (ushort_t)r;
}
__device__ __forceinline__ float bf2f(ushort_t u) {
    union { unsigned int u; float f; } v; v.u = ((unsigned int)u) << 16;
    return v.f;
}
// v_exp_f32 computes 2^x
__device__ __forceinline__ float exp2_(float x) {
    float r; asm("v_exp_f32 %0, %1" : "=v"(r) : "v"(x)); return r;
}
// packed f32 pair -> bf16 pair (lo = a, hi = b)
__device__ __forceinline__ unsigned cvtpk(float a, float b) {
    unsigned r; asm("v_cvt_pk_bf16_f32 %0, %1, %2" : "=v"(r) : "v"(a), "v"(b)); return r;
}
// pull float from lane (byte_addr = src_lane*4)
__device__ __forceinline__ float bperm_f(int byte_addr, float v) {
    union { float f; int i; } u; u.f = v;
    u.i = __builtin_amdgcn_ds_bpermute(byte_addr, u.i);
    return u.f;
}
// async global->LDS, 16B per lane; LDS dest = wave-uniform base + lane*16
__device__ __forceinline__ void gload16(const ushort_t* g, ushort_t* l) {
    __builtin_amdgcn_global_load_lds(
        (const __attribute__((address_space(1))) unsigned int*)g,
        (__attribute__((address_space(3))) unsigned int*)l, 16, 0, 0);
}

// ---------------------------------------------------------------------------
// x fp32 -> bf16, elementwise, 8/thread
// ---------------------------------------------------------------------------
__global__ __launch_bounds__(256)
void convert_x(const float* __restrict__ in, ushort_t* __restrict__ out)
{
    int i = (blockIdx.x * 256 + threadIdx.x) * 8;
    float4 a = ld4(in + i), b = ld4(in + i + 4);
    ushort8_t o;
    o[0] = f2bf(a.x); o[1] = f2bf(a.y); o[2] = f2bf(a.z); o[3] = f2bf(a.w);
    o[4] = f2bf(b.x); o[5] = f2bf(b.y); o[6] = f2bf(b.z); o[7] = f2bf(b.w);
    *(ushort8_t*)(out + i) = o;
}

// ---------------------------------------------------------------------------
// W fp32 [1024][N] -> bf16 W^T [N][1024], 64x64 LDS tiles
// ---------------------------------------------------------------------------
template<int N>
__global__ __launch_bounds__(256)
void transpose_w(const float* __restrict__ in, ushort_t* __restrict__ out)
{
    __shared__ float vs[64][65];
    const int nt = blockIdx.x, kt = blockIdx.y, t = threadIdx.x;
    #pragma unroll
    for (int i = 0; i < 4; ++i) {
        int idx = t + 256 * i;
        int row = idx >> 4, c4 = idx & 15;
        float4 x4 = ld4(in + (size_t)(kt * 64 + row) * N + nt * 64 + c4 * 4);
        vs[row][c4*4+0] = x4.x; vs[row][c4*4+1] = x4.y;
        vs[row][c4*4+2] = x4.z; vs[row][c4*4+3] = x4.w;
    }
    __syncthreads();
    #pragma unroll
    for (int i = 0; i < 16; ++i) {
        int idx = t + 256 * i;
        int nc = idx >> 6, kc = idx & 63;
        out[(size_t)(nt * 64 + nc) * 1024 + kt * 64 + kc] = f2bf(vs[kc][nc]);
    }
}

// ---------------------------------------------------------------------------
// bf16 MFMA GEMM, m97 structure (unchanged, known-correct).
// ---------------------------------------------------------------------------
template<int EPI>
__global__ __launch_bounds__(256)
void bgemm(const ushort_t* __restrict__ A, const ushort_t* __restrict__ Bt,
           float* __restrict__ Cf,
           ushort_t* __restrict__ Qo, ushort_t* __restrict__ Ko, ushort_t* __restrict__ Vo)
{
    constexpr int K = 1024;
    __shared__ ushort_t As[128 * 64];
    __shared__ ushort_t Bs[128 * 64];
    const int t  = threadIdx.x;
    const int l  = t & 63, w = t >> 6;
    const int g  = l >> 4, ln = l & 15;
    const int wr = w >> 1, wc = w & 1;
    const int m0 = blockIdx.y * 128, n0 = blockIdx.x * 128;

    const int srow = w * 8 + (l >> 3);
    const int sch  = (l & 7) ^ (l >> 3);
    const ushort_t* Ag = A  + ((size_t)(m0 + srow)) * K + sch * 8;
    const ushort_t* Bg = Bt + ((size_t)(n0 + srow)) * K + sch * 8;

    f32x4 acc[4][4];
    #pragma unroll
    for (int mi = 0; mi < 4; ++mi)
        #pragma unroll
        for (int nj = 0; nj < 4; ++nj) acc[mi][nj] = f32x4{0.f, 0.f, 0.f, 0.f};

    for (int kt = 0; kt < K / 64; ++kt) {
        #pragma unroll
        for (int i = 0; i < 4; ++i)
            gload16(Ag + (size_t)i * 32 * K + kt * 64, &As[i * 2048 + w * 512]);
        #pragma unroll
        for (int i = 0; i < 4; ++i)
            gload16(Bg + (size_t)i * 32 * K + kt * 64, &Bs[i * 2048 + w * 512]);
        __syncthreads();

        #pragma unroll
        for (int kk = 0; kk < 2; ++kk) {
            bf16x8 af[4], bfv[4];
            #pragma unroll
            for (int mi = 0; mi < 4; ++mi) {
                int row  = 64 * wr + 16 * mi + ln;
                int phys = (4 * kk + g) ^ (ln & 7);
                af[mi] = *(const bf16x8*)&As[row * 64 + phys * 8];
            }
            #pragma unroll
            for (int nj = 0; nj < 4; ++nj) {
                int row  = 64 * wc + 16 * nj + ln;
                int phys = (4 * kk + g) ^ (ln & 7);
                bfv[nj] = *(const bf16x8*)&Bs[row * 64 + phys * 8];
            }
            #pragma unroll
            for (int mi = 0; mi < 4; ++mi)
                #pragma unroll
                for (int nj = 0; nj < 4; ++nj)
                    acc[mi][nj] = MFMA16(af[mi], bfv[nj], acc[mi][nj]);
        }
        __syncthreads();
    }

    if (EPI == 0) {
        #pragma unroll
        for (int mi = 0; mi < 4; ++mi) {
            #pragma unroll
            for (int nj = 0; nj < 4; ++nj) {
                int n = n0 + 64 * wc + 16 * nj + ln;
                #pragma unroll
                for (int r = 0; r < 4; ++r) {
                    int m = m0 + 64 * wr + 16 * mi + 4 * g + r;
                    Cf[(size_t)m * D_ + n] = acc[mi][nj][r];
                }
            }
        }
    } else {
        #pragma unroll
        for (int mi = 0; mi < 4; ++mi) {
            #pragma unroll
            for (int nj = 0; nj < 4; ++nj) {
                int n = n0 + 64 * wc + 16 * nj + ln;
                int which = n >> 10;
                int h  = (n >> 6) & (H_ - 1);
                int dh = n & (DH_ - 1);
                ushort_t* base = (which == 0) ? Qo : ((which == 1) ? Ko : Vo);
                #pragma unroll
                for (int r = 0; r < 4; ++r) {
                    int m = m0 + 64 * wr + 16 * mi + 4 * g + r;
                    int b = m >> 11, ll = m & (L_ - 1);
                    base[((size_t)(b * H_ + h) * L_ + ll) * DH_ + dh] = f2bf(acc[mi][nj][r]);
                }
            }
        }
    }
}

// ---------------------------------------------------------------------------
// RoPE bf16 -> bf16. Q pre-scaled by (1/8)*log2(e) so softmax can use 2^x.
// ---------------------------------------------------------------------------
#define QSCALE (0.125f * 1.44269504088896340736f)
__global__ __launch_bounds__(256)
void rope_bf16(const ushort_t* __restrict__ q, const ushort_t* __restrict__ k,
               ushort_t* __restrict__ qo, ushort_t* __restrict__ ko)
{
    int gid = blockIdx.x * 256 + threadIdx.x;       // B*H*L*8 threads
    int j4  = (gid & 7) * 4;
    int l   = (gid >> 3) & (L_ - 1);
    int bh  = gid >> 14;
    size_t base = ((size_t)bh * L_ + l) * DH_;

    ushort_t a1[4], a2[4], b1[4], b2[4], o1[4], o2[4], p1[4], p2[4];
    *(ushort4*)a1 = *(const ushort4*)(q + base + j4);
    *(ushort4*)a2 = *(const ushort4*)(q + base + j4 + 32);
    *(ushort4*)b1 = *(const ushort4*)(k + base + j4);
    *(ushort4*)b2 = *(const ushort4*)(k + base + j4 + 32);
    #pragma unroll
    for (int jj = 0; jj < 4; ++jj) {
        int j = j4 + jj;
        float inv = powf(10000.0f, -(float)j * (1.0f / 32.0f));
        float s, c;
        sincosf((float)l * inv, &s, &c);
        float q1 = bf2f(a1[jj]), q2 = bf2f(a2[jj]);
        o1[jj] = f2bf((q1 * c - q2 * s) * QSCALE);
        o2[jj] = f2bf((q2 * c + q1 * s) * QSCALE);
        float k1 = bf2f(b1[jj]), k2 = bf2f(b2[jj]);
        p1[jj] = f2bf(k1 * c - k2 * s);
        p2[jj] = f2bf(k2 * c + k1 * s);
    }
    *(ushort4*)(qo + base + j4)      = *(ushort4*)o1;
    *(ushort4*)(qo + base + j4 + 32) = *(ushort4*)o2;
    *(ushort4*)(ko + base + j4)      = *(ushort4*)p1;
    *(ushort4*)(ko + base + j4 + 32) = *(ushort4*)p2;
}

// ---------------------------------------------------------------------------
// V bf16 [bh][L][64] -> vt bf16 [bh][64][L]
// ---------------------------------------------------------------------------
__global__ __launch_bounds__(256)
void transpose_v(const ushort_t* __restrict__ v, ushort_t* __restrict__ vt)
{
    __shared__ ushort_t vs[64][68];
    const int bh = blockIdx.x, lt = blockIdx.y, t = threadIdx.x;
    #pragma unroll
    for (int i = 0; i < 2; ++i) {
        int idx = t + 256 * i;
        int row = idx >> 3, c8 = idx & 7;
        ushort8_t x = *(const ushort8_t*)(v + ((size_t)(bh * L_ + lt * 64 + row)) * 64 + c8 * 8);
        #pragma unroll
        for (int jj = 0; jj < 8; ++jj) vs[row][c8 * 8 + jj] = x[jj];
    }
    __syncthreads();
    #pragma unroll
    for (int i = 0; i < 16; ++i) {
        int idx = t + 256 * i;
        int d = idx >> 6, lc = idx & 63;
        vt[((size_t)(bh * 64 + d)) * L_ + lt * 64 + lc] = vs[lc][d];
    }
}

// ---------------------------------------------------------------------------
// Flash attention v4: SWAPPED QK^T -> S^T = mfma(K_frag, Q_frag) so each
// lane's 16 S values all belong to q=ln. Softmax: 15 in-reg fmax + 2
// shuffles; scalar m/l stats; defer-max (T13, base-2 THR=8); P packed via
// cvt_pk -> 4 ds_write_b64 into row-major [q][key] swizzled LDS; PV A-frag
// is the proven swizzled 16B read. alpha/l broadcast to O rows (q=4g+r)
// via ds_bpermute from lane 4g+r. K/V staging identical to R5 (proven).
// Layouts: A: lane holds A[ln][32kk+8g+j]; B: lane holds Bt[ln][32kk+8g+j];
//          D: lane reg r -> D[4g+r][ln]   (g=lane>>4, ln=lane&15)
// ---------------------------------------------------------------------------
__global__ __launch_bounds__(256)
void attn_mfma(const ushort_t* __restrict__ qb, const ushort_t* __restrict__ kb,
               const ushort_t* __restrict__ vt, ushort_t* __restrict__ ao)
{
    __shared__ ushort_t Ks[2][64 * 64];     // [key][d], swizzled chunks
    __shared__ ushort_t Vs[2][64 * 64];     // [d][key], swizzled chunks
    __shared__ ushort_t Ps[4][16 * 64];     // per-wave P [16 q][64 key], swizzled

    const int t    = threadIdx.x;
    const int lane = t & 63, wv = t >> 6;
    const int g    = lane >> 4, ln = lane & 15;
    const int bh   = blockIdx.x;
    const int q0   = blockIdx.y * 64 + wv * 16;

    // Q fragments straight from global: lane holds Q[q0+ln][32kk+8g+j]
    const ushort_t* qp = qb + ((size_t)bh * L_ + q0 + ln) * DH_;
    bf16x8 qf0 = *(const bf16x8*)(qp + 8 * g);
    bf16x8 qf1 = *(const bf16x8*)(qp + 32 + 8 * g);

    const ushort_t* kp = kb + (size_t)bh * L_ * DH_;
    const ushort_t* vp = vt + (size_t)bh * DH_ * L_;

    // staging geometry: lane covers row srow+8i, phys chunk l&7, source chunk sch
    const int srow = 16 * wv + (lane >> 3);
    const int sch  = (lane & 7) ^ (lane >> 3);

    char* Pw = (char*)&Ps[wv][0];
    const int swz = (ln & 7) << 4;

    f32x4 O[4];
    #pragma unroll
    for (int n = 0; n < 4; ++n) O[n] = f32x4{0.f, 0.f, 0.f, 0.f};
    float m_q = -INFINITY, l_q = 0.f;   // stats for q = ln (replicated over g)

    // prologue: tile 0 -> buf 0 (4 loads per wave)
    #pragma unroll
    for (int i = 0; i < 2; ++i) {
        gload16(kp + ((size_t)(srow + 8 * i)) * 64 + sch * 8,
                &Ks[0][(16 * wv + 8 * i) * 64]);
        gload16(vp + ((size_t)(srow + 8 * i)) * L_ + sch * 8,
                &Vs[0][(16 * wv + 8 * i) * 64]);
    }

    for (int kt = 0; kt < L_ / 64; ++kt) {
        const int cur = kt & 1, nxt = cur ^ 1;
        const int nk  = (kt < L_ / 64 - 1) ? kt + 1 : kt;   // clamp: redundant reload
        #pragma unroll
        for (int i = 0; i < 2; ++i) {
            gload16(kp + ((size_t)(nk * 64 + srow + 8 * i)) * 64 + sch * 8,
                    &Ks[nxt][(16 * wv + 8 * i) * 64]);
            gload16(vp + ((size_t)(srow + 8 * i)) * L_ + nk * 64 + sch * 8,
                    &Vs[nxt][(16 * wv + 8 * i) * 64]);
        }
        asm volatile("s_waitcnt vmcnt(4)" ::: "memory");  // my tile-kt loads landed
        __builtin_amdgcn_s_barrier();                      // landed for ALL waves
        asm volatile("" ::: "memory");   // fence: no LDS reads above the barrier

        const ushort_t* Kc = &Ks[cur][0];
        const ushort_t* Vc = &Vs[cur][0];

        // ---- swapped QK^T: S[n][r] = S^T[key=16n+4g+r][q=ln] ----
        f32x4 S[4];
        #pragma unroll
        for (int n = 0; n < 4; ++n) S[n] = f32x4{0.f, 0.f, 0.f, 0.f};
        bf16x8 kf[2][4];
        #pragma unroll
        for (int kk = 0; kk < 2; ++kk)
            #pragma unroll
            for (int n = 0; n < 4; ++n) {
                int row  = 16 * n + ln;
                int phys = (4 * kk + g) ^ (ln & 7);
                kf[kk][n] = *(const bf16x8*)&Kc[row * 64 + phys * 8];
            }
        __builtin_amdgcn_s_setprio(1);
        #pragma unroll
        for (int kk = 0; kk < 2; ++kk) {
            bf16x8 b = kk ? qf1 : qf0;
            #pragma unroll
            for (int n = 0; n < 4; ++n) S[n] = MFMA16(kf[kk][n], b, S[n]);
        }
        __builtin_amdgcn_s_setprio(0);

        // ---- softmax for q=ln: in-register row max over 16, 2 shuffles ----
        float pmax;
        {
            float m0 = fmaxf(fmaxf(S[0][0], S[0][1]), fmaxf(S[0][2], S[0][3]));
            float m1 = fmaxf(fmaxf(S[1][0], S[1][1]), fmaxf(S[1][2], S[1][3]));
            float m2 = fmaxf(fmaxf(S[2][0], S[2][1]), fmaxf(S[2][2], S[2][3]));
            float m3 = fmaxf(fmaxf(S[3][0], S[3][1]), fmaxf(S[3][2], S[3][3]));
            pmax = fmaxf(fmaxf(m0, m1), fmaxf(m2, m3));
        }
        pmax = fmaxf(pmax, __shfl_xor(pmax, 16));
        pmax = fmaxf(pmax, __shfl_xor(pmax, 32));

        // defer-max (T13): rescale only when the max moved by > 8 (2^8 bound)
        if (!__all(pmax - m_q <= 8.0f)) {
            float mnew = fmaxf(m_q, pmax);
            float al   = exp2_(m_q - mnew);
            m_q = mnew;
            l_q *= al;
            #pragma unroll
            for (int r = 0; r < 4; ++r) {
                float alr = bperm_f((4 * g + r) * 4, al);   // stats for q=4g+r
                #pragma unroll
                for (int n = 0; n < 4; ++n) O[n][r] *= alr;
            }
        }

        // ---- P = 2^(S - m), packed cvt_pk -> b64 stores into P[q=ln][key] ----
        float psum = 0.f;
        #pragma unroll
        for (int n = 0; n < 4; ++n) {
            float p0 = exp2_(S[n][0] - m_q);
            float p1 = exp2_(S[n][1] - m_q);
            float p2 = exp2_(S[n][2] - m_q);
            float p3 = exp2_(S[n][3] - m_q);
            psum += (p0 + p1) + (p2 + p3);
            uintx2 wq;
            wq[0] = cvtpk(p0, p1);
            wq[1] = cvtpk(p2, p3);
            *(uintx2*)(Pw + 128 * ln + ((32 * n + 8 * g) ^ swz)) = wq;
        }
        psum += __shfl_xor(psum, 16);
        psum += __shfl_xor(psum, 32);
        l_q += psum;

        // ---- PV (P wave-private; same-wave DS in-order; no barrier) ----
        #pragma unroll
        for (int kk = 0; kk < 2; ++kk) {
            bf16x8 pa = *(const bf16x8*)(Pw + 128 * ln + ((64 * kk + 16 * g) ^ swz));
            bf16x8 vf[4];
            #pragma unroll
            for (int n = 0; n < 4; ++n) {
                int vrow = 16 * n + ln;
                int voff = vrow * 64 + (((64 * kk + 16 * g) ^ ((vrow & 7) << 4)) >> 1);
                vf[n] = *(const bf16x8*)&Vc[voff];
            }
            __builtin_amdgcn_s_setprio(1);
            #pragma unroll
            for (int n = 0; n < 4; ++n) O[n] = MFMA16(pa, vf[n], O[n]);
            __builtin_amdgcn_s_setprio(0);
        }

        __builtin_amdgcn_s_barrier();    // all waves done reading buf[cur]
        asm volatile("" ::: "memory");   // fence: next staging stays below
    }
    asm volatile("s_waitcnt vmcnt(0)" ::: "memory");  // drain redundant tail loads

    // epilogue: pull l for q=4g+r, normalize, write bf16 ao [B][L][D]
    const int b = bh >> 4, h = bh & 15;
    #pragma unroll
    for (int r = 0; r < 4; ++r) {
        float lb  = bperm_f((4 * g + r) * 4, l_q);
        float inv = 1.0f / lb;
        int ql = q0 + 4 * g + r;
        ushort_t* dst = ao + ((size_t)(b * L_ + ql)) * D_ + h * 64;
        #pragma unroll
        for (int n = 0; n < 4; ++n)
            dst[16 * n + ln] = f2bf(O[n][r] * inv);
    }
}

// ---------------------------------------------------------------------------
extern "C" void kernel_launch(void* const* d_in, const int* in_sizes, int n_in,
                              void* d_out, int out_size, void* d_ws, size_t ws_size,
                              hipStream_t stream)
{
    const float* x    = (const float*)d_in[0];
    const float* Wqkv = (const float*)d_in[1];
    const float* Wo   = (const float*)d_in[2];
    float* out = (float*)d_out;

    char* ws = (char*)d_ws;                               // 64 MB layout:
    ushort_t* xb  = (ushort_t*)(ws);                      // [0,8M)   x bf16; later ao
    ushort_t* wqt = (ushort_t*)(ws + ((size_t) 8 << 20)); // [8,14M)  Wqkv^T bf16
    ushort_t* wot = (ushort_t*)(ws + ((size_t)14 << 20)); // [14,16M) Wo^T bf16
    ushort_t* qB  = (ushort_t*)(ws + ((size_t)16 << 20)); // [16,24M) q pre-rope
    ushort_t* kB  = (ushort_t*)(ws + ((size_t)24 << 20)); // [24,32M) k pre-rope
    ushort_t* vB  = (ushort_t*)(ws + ((size_t)32 << 20)); // [32,40M) v
    ushort_t* qR  = (ushort_t*)(ws + ((size_t)40 << 20)); // [40,48M) q rope'd
    ushort_t* kR  = (ushort_t*)(ws + ((size_t)48 << 20)); // [48,56M) k rope'd
    ushort_t* vt  = (ushort_t*)(ws + ((size_t)56 << 20)); // [56,64M) v^T
    ushort_t* ao  = xb;                                   // alias (xb dead post-gemm)

    convert_x<<<(M_ * D_) / (8 * 256), 256, 0, stream>>>(x, xb);
    transpose_w<N1_><<<dim3(N1_ / 64, 16), 256, 0, stream>>>(Wqkv, wqt);
    transpose_w<D_ ><<<dim3(D_  / 64, 16), 256, 0, stream>>>(Wo, wot);

    bgemm<1><<<dim3(N1_ / 128, M_ / 128), 256, 0, stream>>>(xb, wqt, nullptr, qB, kB, vB);
    rope_bf16<<<(B_ * H_ * L_ * 8) / 256, 256, 0, stream>>>(qB, kB, qR, kR);
    transpose_v<<<dim3(B_ * H_, L_ / 64), 256, 0, stream>>>(vB, vt);
    attn_mfma<<<dim3(B_ * H_, L_ / 64), 256, 0, stream>>>(qR, kR, vt, ao);
    bgemm<0><<<dim3(D_ / 128, M_ / 128), 256, 0, stream>>>(ao, wot, out, nullptr, nullptr, nullptr);
}

// Round 7
// 152.173 us; speedup vs baseline: 7.2693x; 1.0317x over previous
//
#include <hip/hip_runtime.h>
#include <hip/hip_bf16.h>

#define B_  2
#define L_  2048
#define D_  1024
#define H_  16
#define DH_ 64
#define M_  (B_*L_)     // 4096
#define N1_ (3*D_)      // 3072

typedef __bf16 bf16x8 __attribute__((ext_vector_type(8)));
typedef float  f32x4  __attribute__((ext_vector_type(4)));
typedef unsigned short ushort_t;
typedef unsigned short ushort8_t __attribute__((ext_vector_type(8)));
typedef unsigned int   uintx2    __attribute__((ext_vector_type(2)));

#define MFMA16(a,b,c) __builtin_amdgcn_mfma_f32_16x16x32_bf16((a),(b),(c),0,0,0)

__device__ __forceinline__ float4 ld4(const float* p) { return *(const float4*)p; }

__device__ __forceinline__ ushort_t f2bf(float f) {
    union { float f; unsigned int u; } v; v.f = f;
    unsigned int r = (v.u + 0x7FFFu + ((v.u >> 16) & 1u)) >> 16;
    return (ushort_t)r;
}
__device__ __forceinline__ float bf2f(ushort_t u) {
    union { unsigned int u; float f; } v; v.u = ((unsigned int)u) << 16;
    return v.f;
}
// v_exp_f32 computes 2^x
__device__ __forceinline__ float exp2_(float x) {
    float r; asm("v_exp_f32 %0, %1" : "=v"(r) : "v"(x)); return r;
}
// packed f32 pair -> bf16 pair (lo = a, hi = b)
__device__ __forceinline__ unsigned cvtpk(float a, float b) {
    unsigned r; asm("v_cvt_pk_bf16_f32 %0, %1, %2" : "=v"(r) : "v"(a), "v"(b)); return r;
}
// pull float from lane (byte_addr = src_lane*4)
__device__ __forceinline__ float bperm_f(int byte_addr, float v) {
    union { float f; int i; } u; u.f = v;
    u.i = __builtin_amdgcn_ds_bpermute(byte_addr, u.i);
    return u.f;
}
// async global->LDS, 16B per lane; LDS dest = wave-uniform base + lane*16
__device__ __forceinline__ void gload16(const ushort_t* g, ushort_t* l) {
    __builtin_amdgcn_global_load_lds(
        (const __attribute__((address_space(1))) unsigned int*)g,
        (__attribute__((address_space(3))) unsigned int*)l, 16, 0, 0);
}

// ---------------------------------------------------------------------------
// x fp32 -> bf16, elementwise, 8/thread
// ---------------------------------------------------------------------------
__global__ __launch_bounds__(256)
void convert_x(const float* __restrict__ in, ushort_t* __restrict__ out)
{
    int i = (blockIdx.x * 256 + threadIdx.x) * 8;
    float4 a = ld4(in + i), b = ld4(in + i + 4);
    ushort8_t o;
    o[0] = f2bf(a.x); o[1] = f2bf(a.y); o[2] = f2bf(a.z); o[3] = f2bf(a.w);
    o[4] = f2bf(b.x); o[5] = f2bf(b.y); o[6] = f2bf(b.z); o[7] = f2bf(b.w);
    *(ushort8_t*)(out + i) = o;
}

// ---------------------------------------------------------------------------
// W fp32 [1024][N] -> bf16 W^T [N][1024], 64x64 LDS tiles
// ---------------------------------------------------------------------------
template<int N>
__global__ __launch_bounds__(256)
void transpose_w(const float* __restrict__ in, ushort_t* __restrict__ out)
{
    __shared__ float vs[64][65];
    const int nt = blockIdx.x, kt = blockIdx.y, t = threadIdx.x;
    #pragma unroll
    for (int i = 0; i < 4; ++i) {
        int idx = t + 256 * i;
        int row = idx >> 4, c4 = idx & 15;
        float4 x4 = ld4(in + (size_t)(kt * 64 + row) * N + nt * 64 + c4 * 4);
        vs[row][c4*4+0] = x4.x; vs[row][c4*4+1] = x4.y;
        vs[row][c4*4+2] = x4.z; vs[row][c4*4+3] = x4.w;
    }
    __syncthreads();
    #pragma unroll
    for (int i = 0; i < 16; ++i) {
        int idx = t + 256 * i;
        int nc = idx >> 6, kc = idx & 63;
        out[(size_t)(nt * 64 + nc) * 1024 + kt * 64 + kc] = f2bf(vs[kc][nc]);
    }
}

// ---------------------------------------------------------------------------
// bf16 MFMA GEMM, m97 structure. EPI 0: fp32 C. EPI 1: QKV scatter with
// V written TRANSPOSED (vt [bh][64 d][L]) so transpose_v is not needed.
// ---------------------------------------------------------------------------
template<int EPI>
__global__ __launch_bounds__(256)
void bgemm(const ushort_t* __restrict__ A, const ushort_t* __restrict__ Bt,
           float* __restrict__ Cf,
           ushort_t* __restrict__ Qo, ushort_t* __restrict__ Ko, ushort_t* __restrict__ Vo)
{
    constexpr int K = 1024;
    __shared__ ushort_t As[128 * 64];
    __shared__ ushort_t Bs[128 * 64];
    const int t  = threadIdx.x;
    const int l  = t & 63, w = t >> 6;
    const int g  = l >> 4, ln = l & 15;
    const int wr = w >> 1, wc = w & 1;
    const int m0 = blockIdx.y * 128, n0 = blockIdx.x * 128;

    const int srow = w * 8 + (l >> 3);
    const int sch  = (l & 7) ^ (l >> 3);
    const ushort_t* Ag = A  + ((size_t)(m0 + srow)) * K + sch * 8;
    const ushort_t* Bg = Bt + ((size_t)(n0 + srow)) * K + sch * 8;

    f32x4 acc[4][4];
    #pragma unroll
    for (int mi = 0; mi < 4; ++mi)
        #pragma unroll
        for (int nj = 0; nj < 4; ++nj) acc[mi][nj] = f32x4{0.f, 0.f, 0.f, 0.f};

    for (int kt = 0; kt < K / 64; ++kt) {
        #pragma unroll
        for (int i = 0; i < 4; ++i)
            gload16(Ag + (size_t)i * 32 * K + kt * 64, &As[i * 2048 + w * 512]);
        #pragma unroll
        for (int i = 0; i < 4; ++i)
            gload16(Bg + (size_t)i * 32 * K + kt * 64, &Bs[i * 2048 + w * 512]);
        __syncthreads();

        #pragma unroll
        for (int kk = 0; kk < 2; ++kk) {
            bf16x8 af[4], bfv[4];
            #pragma unroll
            for (int mi = 0; mi < 4; ++mi) {
                int row  = 64 * wr + 16 * mi + ln;
                int phys = (4 * kk + g) ^ (ln & 7);
                af[mi] = *(const bf16x8*)&As[row * 64 + phys * 8];
            }
            #pragma unroll
            for (int nj = 0; nj < 4; ++nj) {
                int row  = 64 * wc + 16 * nj + ln;
                int phys = (4 * kk + g) ^ (ln & 7);
                bfv[nj] = *(const bf16x8*)&Bs[row * 64 + phys * 8];
            }
            #pragma unroll
            for (int mi = 0; mi < 4; ++mi)
                #pragma unroll
                for (int nj = 0; nj < 4; ++nj)
                    acc[mi][nj] = MFMA16(af[mi], bfv[nj], acc[mi][nj]);
        }
        __syncthreads();
    }

    if (EPI == 0) {
        #pragma unroll
        for (int mi = 0; mi < 4; ++mi) {
            #pragma unroll
            for (int nj = 0; nj < 4; ++nj) {
                int n = n0 + 64 * wc + 16 * nj + ln;
                #pragma unroll
                for (int r = 0; r < 4; ++r) {
                    int m = m0 + 64 * wr + 16 * mi + 4 * g + r;
                    Cf[(size_t)m * D_ + n] = acc[mi][nj][r];
                }
            }
        }
    } else {
        #pragma unroll
        for (int mi = 0; mi < 4; ++mi) {
            #pragma unroll
            for (int nj = 0; nj < 4; ++nj) {
                int n = n0 + 64 * wc + 16 * nj + ln;
                int which = n >> 10;
                int h  = (n >> 6) & (H_ - 1);
                int dh = n & (DH_ - 1);
                #pragma unroll
                for (int r = 0; r < 4; ++r) {
                    int m = m0 + 64 * wr + 16 * mi + 4 * g + r;
                    int b = m >> 11, ll = m & (L_ - 1);
                    ushort_t val = f2bf(acc[mi][nj][r]);
                    if (which == 2) {   // V: transposed scatter [bh][d][L]
                        Vo[((size_t)(b * H_ + h) * DH_ + dh) * L_ + ll] = val;
                    } else {
                        ushort_t* base = (which == 0) ? Qo : Ko;
                        base[((size_t)(b * H_ + h) * L_ + ll) * DH_ + dh] = val;
                    }
                }
            }
        }
    }
}

// ---------------------------------------------------------------------------
// RoPE bf16 -> bf16. Q pre-scaled by (1/8)*log2(e) so softmax can use 2^x.
// ---------------------------------------------------------------------------
#define QSCALE (0.125f * 1.44269504088896340736f)
__global__ __launch_bounds__(256)
void rope_bf16(const ushort_t* __restrict__ q, const ushort_t* __restrict__ k,
               ushort_t* __restrict__ qo, ushort_t* __restrict__ ko)
{
    int gid = blockIdx.x * 256 + threadIdx.x;       // B*H*L*8 threads
    int j4  = (gid & 7) * 4;
    int l   = (gid >> 3) & (L_ - 1);
    int bh  = gid >> 14;
    size_t base = ((size_t)bh * L_ + l) * DH_;

    ushort_t a1[4], a2[4], b1[4], b2[4], o1[4], o2[4], p1[4], p2[4];
    *(ushort4*)a1 = *(const ushort4*)(q + base + j4);
    *(ushort4*)a2 = *(const ushort4*)(q + base + j4 + 32);
    *(ushort4*)b1 = *(const ushort4*)(k + base + j4);
    *(ushort4*)b2 = *(const ushort4*)(k + base + j4 + 32);
    #pragma unroll
    for (int jj = 0; jj < 4; ++jj) {
        int j = j4 + jj;
        float inv = powf(10000.0f, -(float)j * (1.0f / 32.0f));
        float s, c;
        sincosf((float)l * inv, &s, &c);
        float q1 = bf2f(a1[jj]), q2 = bf2f(a2[jj]);
        o1[jj] = f2bf((q1 * c - q2 * s) * QSCALE);
        o2[jj] = f2bf((q2 * c + q1 * s) * QSCALE);
        float k1 = bf2f(b1[jj]), k2 = bf2f(b2[jj]);
        p1[jj] = f2bf(k1 * c - k2 * s);
        p2[jj] = f2bf(k2 * c + k1 * s);
    }
    *(ushort4*)(qo + base + j4)      = *(ushort4*)o1;
    *(ushort4*)(qo + base + j4 + 32) = *(ushort4*)o2;
    *(ushort4*)(ko + base + j4)      = *(ushort4*)p1;
    *(ushort4*)(ko + base + j4 + 32) = *(ushort4*)p2;
}

// ---------------------------------------------------------------------------
// Flash attention v5: 32 q-rows per wave (two 16-row halves sharing the
// same K/V fragments, staging and barriers -> 2x MFMA per fixed cost).
// Swapped QK^T, defer-max, packed P, R5-proven staging/barrier structure.
// Layouts: A: lane holds A[ln][32kk+8g+j]; B: lane holds Bt[ln][32kk+8g+j];
//          D: lane reg r -> D[4g+r][ln]   (g=lane>>4, ln=lane&15)
// ---------------------------------------------------------------------------
__global__ __launch_bounds__(256)
void attn_mfma(const ushort_t* __restrict__ qb, const ushort_t* __restrict__ kb,
               const ushort_t* __restrict__ vt, ushort_t* __restrict__ ao)
{
    __shared__ ushort_t Ks[2][64 * 64];     // [key][d], swizzled chunks
    __shared__ ushort_t Vs[2][64 * 64];     // [d][key], swizzled chunks
    __shared__ ushort_t Ps[4][32 * 64];     // per-wave P [32 q][64 key], swizzled

    const int t    = threadIdx.x;
    const int lane = t & 63, wv = t >> 6;
    const int g    = lane >> 4, ln = lane & 15;
    const int bh   = blockIdx.x;
    const int q0   = blockIdx.y * 128 + wv * 32;

    // Q fragments: half h covers rows q0+16h+ln
    const ushort_t* qpA = qb + ((size_t)bh * L_ + q0 + ln) * DH_;
    bf16x8 qf[2][2];
    qf[0][0] = *(const bf16x8*)(qpA + 8 * g);
    qf[0][1] = *(const bf16x8*)(qpA + 32 + 8 * g);
    qf[1][0] = *(const bf16x8*)(qpA + 16 * DH_ + 8 * g);
    qf[1][1] = *(const bf16x8*)(qpA + 16 * DH_ + 32 + 8 * g);

    const ushort_t* kp = kb + (size_t)bh * L_ * DH_;
    const ushort_t* vp = vt + (size_t)bh * DH_ * L_;

    // staging geometry: lane covers row srow+8i, phys chunk l&7, source chunk sch
    const int srow = 16 * wv + (lane >> 3);
    const int sch  = (lane & 7) ^ (lane >> 3);

    char* Pw = (char*)&Ps[wv][0];           // half h at byte offset 2048*h
    const int swz = (ln & 7) << 4;

    f32x4 O[2][4];
    #pragma unroll
    for (int h = 0; h < 2; ++h)
        #pragma unroll
        for (int n = 0; n < 4; ++n) O[h][n] = f32x4{0.f, 0.f, 0.f, 0.f};
    float m_q[2] = {-INFINITY, -INFINITY}, l_q[2] = {0.f, 0.f};

    // prologue: tile 0 -> buf 0 (4 loads per wave)
    #pragma unroll
    for (int i = 0; i < 2; ++i) {
        gload16(kp + ((size_t)(srow + 8 * i)) * 64 + sch * 8,
                &Ks[0][(16 * wv + 8 * i) * 64]);
        gload16(vp + ((size_t)(srow + 8 * i)) * L_ + sch * 8,
                &Vs[0][(16 * wv + 8 * i) * 64]);
    }

    for (int kt = 0; kt < L_ / 64; ++kt) {
        const int cur = kt & 1, nxt = cur ^ 1;
        const int nk  = (kt < L_ / 64 - 1) ? kt + 1 : kt;   // clamp: redundant reload
        #pragma unroll
        for (int i = 0; i < 2; ++i) {
            gload16(kp + ((size_t)(nk * 64 + srow + 8 * i)) * 64 + sch * 8,
                    &Ks[nxt][(16 * wv + 8 * i) * 64]);
            gload16(vp + ((size_t)(srow + 8 * i)) * L_ + nk * 64 + sch * 8,
                    &Vs[nxt][(16 * wv + 8 * i) * 64]);
        }
        asm volatile("s_waitcnt vmcnt(4)" ::: "memory");  // my tile-kt loads landed
        __builtin_amdgcn_s_barrier();                      // landed for ALL waves
        asm volatile("" ::: "memory");   // fence: no LDS reads above the barrier

        const ushort_t* Kc = &Ks[cur][0];
        const ushort_t* Vc = &Vs[cur][0];

        // ---- swapped QK^T: S[h][n][r] = S^T[key=16n+4g+r][q=16h+ln] ----
        f32x4 S[2][4];
        #pragma unroll
        for (int h = 0; h < 2; ++h)
            #pragma unroll
            for (int n = 0; n < 4; ++n) S[h][n] = f32x4{0.f, 0.f, 0.f, 0.f};
        #pragma unroll
        for (int kk = 0; kk < 2; ++kk) {
            bf16x8 kfv[4];
            #pragma unroll
            for (int n = 0; n < 4; ++n) {
                int row  = 16 * n + ln;
                int phys = (4 * kk + g) ^ (ln & 7);
                kfv[n] = *(const bf16x8*)&Kc[row * 64 + phys * 8];
            }
            __builtin_amdgcn_s_setprio(1);
            #pragma unroll
            for (int n = 0; n < 4; ++n) S[0][n] = MFMA16(kfv[n], qf[0][kk], S[0][n]);
            #pragma unroll
            for (int n = 0; n < 4; ++n) S[1][n] = MFMA16(kfv[n], qf[1][kk], S[1][n]);
            __builtin_amdgcn_s_setprio(0);
        }

        // ---- softmax per half (q = 16h + ln) ----
        #pragma unroll
        for (int h = 0; h < 2; ++h) {
            float pmax;
            {
                float a0 = fmaxf(fmaxf(S[h][0][0], S[h][0][1]), fmaxf(S[h][0][2], S[h][0][3]));
                float a1 = fmaxf(fmaxf(S[h][1][0], S[h][1][1]), fmaxf(S[h][1][2], S[h][1][3]));
                float a2 = fmaxf(fmaxf(S[h][2][0], S[h][2][1]), fmaxf(S[h][2][2], S[h][2][3]));
                float a3 = fmaxf(fmaxf(S[h][3][0], S[h][3][1]), fmaxf(S[h][3][2], S[h][3][3]));
                pmax = fmaxf(fmaxf(a0, a1), fmaxf(a2, a3));
            }
            pmax = fmaxf(pmax, __shfl_xor(pmax, 16));
            pmax = fmaxf(pmax, __shfl_xor(pmax, 32));

            if (!__all(pmax - m_q[h] <= 8.0f)) {   // defer-max (T13)
                float mnew = fmaxf(m_q[h], pmax);
                float al   = exp2_(m_q[h] - mnew);
                m_q[h] = mnew;
                l_q[h] *= al;
                #pragma unroll
                for (int r = 0; r < 4; ++r) {
                    float alr = bperm_f((4 * g + r) * 4, al);
                    #pragma unroll
                    for (int n = 0; n < 4; ++n) O[h][n][r] *= alr;
                }
            }

            float psum = 0.f;
            #pragma unroll
            for (int n = 0; n < 4; ++n) {
                float p0 = exp2_(S[h][n][0] - m_q[h]);
                float p1 = exp2_(S[h][n][1] - m_q[h]);
                float p2 = exp2_(S[h][n][2] - m_q[h]);
                float p3 = exp2_(S[h][n][3] - m_q[h]);
                psum += (p0 + p1) + (p2 + p3);
                uintx2 wq;
                wq[0] = cvtpk(p0, p1);
                wq[1] = cvtpk(p2, p3);
                *(uintx2*)(Pw + 2048 * h + 128 * ln + ((32 * n + 8 * g) ^ swz)) = wq;
            }
            psum += __shfl_xor(psum, 16);
            psum += __shfl_xor(psum, 32);
            l_q[h] += psum;
        }

        // ---- PV (P wave-private; same-wave DS in-order; no barrier) ----
        #pragma unroll
        for (int kk = 0; kk < 2; ++kk) {
            bf16x8 vfv[4];
            #pragma unroll
            for (int n = 0; n < 4; ++n) {
                int vrow = 16 * n + ln;
                int voff = vrow * 64 + (((64 * kk + 16 * g) ^ ((vrow & 7) << 4)) >> 1);
                vfv[n] = *(const bf16x8*)&Vc[voff];
            }
            bf16x8 pa0 = *(const bf16x8*)(Pw + 128 * ln + ((64 * kk + 16 * g) ^ swz));
            bf16x8 pa1 = *(const bf16x8*)(Pw + 2048 + 128 * ln + ((64 * kk + 16 * g) ^ swz));
            __builtin_amdgcn_s_setprio(1);
            #pragma unroll
            for (int n = 0; n < 4; ++n) O[0][n] = MFMA16(pa0, vfv[n], O[0][n]);
            #pragma unroll
            for (int n = 0; n < 4; ++n) O[1][n] = MFMA16(pa1, vfv[n], O[1][n]);
            __builtin_amdgcn_s_setprio(0);
        }

        __builtin_amdgcn_s_barrier();    // all waves done reading buf[cur]
        asm volatile("" ::: "memory");   // fence: next staging stays below
    }
    asm volatile("s_waitcnt vmcnt(0)" ::: "memory");  // drain redundant tail loads

    // epilogue: pull l for q=16h+4g+r, normalize, write bf16 ao [B][L][D]
    const int b = bh >> 4, hh = bh & 15;
    #pragma unroll
    for (int h = 0; h < 2; ++h) {
        #pragma unroll
        for (int r = 0; r < 4; ++r) {
            float lb  = bperm_f((4 * g + r) * 4, l_q[h]);
            float inv = 1.0f / lb;
            int ql = q0 + 16 * h + 4 * g + r;
            ushort_t* dst = ao + ((size_t)(b * L_ + ql)) * D_ + hh * 64;
            #pragma unroll
            for (int n = 0; n < 4; ++n)
                dst[16 * n + ln] = f2bf(O[h][n][r] * inv);
        }
    }
}

// ---------------------------------------------------------------------------
extern "C" void kernel_launch(void* const* d_in, const int* in_sizes, int n_in,
                              void* d_out, int out_size, void* d_ws, size_t ws_size,
                              hipStream_t stream)
{
    const float* x    = (const float*)d_in[0];
    const float* Wqkv = (const float*)d_in[1];
    const float* Wo   = (const float*)d_in[2];
    float* out = (float*)d_out;

    char* ws = (char*)d_ws;                               // 64 MB layout:
    ushort_t* xb  = (ushort_t*)(ws);                      // [0,8M)   x bf16; later ao
    ushort_t* wqt = (ushort_t*)(ws + ((size_t) 8 << 20)); // [8,14M)  Wqkv^T bf16
    ushort_t* wot = (ushort_t*)(ws + ((size_t)14 << 20)); // [14,16M) Wo^T bf16
    ushort_t* qB  = (ushort_t*)(ws + ((size_t)16 << 20)); // [16,24M) q pre-rope
    ushort_t* kB  = (ushort_t*)(ws + ((size_t)24 << 20)); // [24,32M) k pre-rope
    ushort_t* vt  = (ushort_t*)(ws + ((size_t)32 << 20)); // [32,40M) v^T (from GEMM)
    ushort_t* qR  = (ushort_t*)(ws + ((size_t)40 << 20)); // [40,48M) q rope'd
    ushort_t* kR  = (ushort_t*)(ws + ((size_t)48 << 20)); // [48,56M) k rope'd
    ushort_t* ao  = xb;                                   // alias (xb dead post-gemm)

    convert_x<<<(M_ * D_) / (8 * 256), 256, 0, stream>>>(x, xb);
    transpose_w<N1_><<<dim3(N1_ / 64, 16), 256, 0, stream>>>(Wqkv, wqt);
    transpose_w<D_ ><<<dim3(D_  / 64, 16), 256, 0, stream>>>(Wo, wot);

    bgemm<1><<<dim3(N1_ / 128, M_ / 128), 256, 0, stream>>>(xb, wqt, nullptr, qB, kB, vt);
    rope_bf16<<<(B_ * H_ * L_ * 8) / 256, 256, 0, stream>>>(qB, kB, qR, kR);
    attn_mfma<<<dim3(B_ * H_, L_ / 128), 256, 0, stream>>>(qR, kR, vt, ao);
    bgemm<0><<<dim3(D_ / 128, M_ / 128), 256, 0, stream>>>(ao, wot, out, nullptr, nullptr, nullptr);
}